// Round 6
// baseline (338.685 us; speedup 1.0000x reference)
//
#include <hip/hip_runtime.h>

// CvT block, MI355X bf16-MFMA implementation.
// B=32, C=128, L=32 (seq=1024), H=8, DK=64, HD=512, NLAYER=4.
// R6: attn was LDS-pipe bound (336 cyc/wave-iter staged K/V + P roundtrip
// ≈ 92us of 115us). K and V are now stored in MFMA B-fragment order by
// qkv_gemm and loaded straight from global (L1/L2) in attn — no staging,
// no barriers, LDS carries only the per-wave P transpose.

#define NB   32
#define NH   8
#define SEQ  1024
#define DKH  64
#define HDIM 512
#define CIN  128

// 0.125 * log2(e): folded into Wq and bias so scores are in exp2 domain.
#define SCL 0.18033688011112042f

typedef __bf16 bf16x8 __attribute__((ext_vector_type(8)));
typedef float floatx4 __attribute__((ext_vector_type(4)));
typedef unsigned short u16x8 __attribute__((ext_vector_type(8)));

__device__ __forceinline__ unsigned short f2bf(float f) {
    union { float f; unsigned int u; } c; c.f = f;
    unsigned int u = c.u;
    return (unsigned short)((u + 0x7fffu + ((u >> 16) & 1u)) >> 16); // RNE
}
__device__ __forceinline__ bf16x8 ldfrag(const unsigned short* p) {
    u16x8 v = *reinterpret_cast<const u16x8*>(p);
    return __builtin_bit_cast(bf16x8, v);
}
__device__ __forceinline__ float bfhi(unsigned int u) {  // low short -> f32
    return __builtin_bit_cast(float, u << 16);
}
__device__ __forceinline__ float bflo(unsigned int u) {  // high short -> f32
    return __builtin_bit_cast(float, u & 0xFFFF0000u);
}
// pack two f32 -> two RNE bf16; 'a' lands in the LOW short.
__device__ __forceinline__ unsigned int pkbf(float a, float b) {
    unsigned int ua = __builtin_bit_cast(unsigned int, a);
    unsigned int ub = __builtin_bit_cast(unsigned int, b);
    ua += 0x7fffu + ((ua >> 16) & 1u);
    ub += 0x7fffu + ((ub >> 16) & 1u);
    return __builtin_amdgcn_perm(ub, ua, 0x07060302u);
}

// Fragment-order storage: a 512-elem block holds one wave B/A fragment,
// [lane=q*16+n][j=0..7]; a wave's fragment load = base + lane*8 = 1KB burst.
// Kf: frag (s,c) lane (q,n) j  <->  K[key = 4n+s (permuted)][d = 32c+8q+j]
//     Kf[((bh*16+kt)*8 + s*2+c)*512 + lane*8 + j]
// Vf: frag (u,c) lane (q,n) j  <->  V[d = 16u+n][j_local = 32c+8q+j]
//     Vf[((bh*16+kt)*8 + u*2+c)*512 + lane*8 + j]

// ---------------- prep: weights + swizzled bias ----------------
__global__ __launch_bounds__(256) void prep_wb(const float* __restrict__ Wq,
                                               const float* __restrict__ Wk,
                                               const float* __restrict__ Wv,
                                               const float* __restrict__ W0,
                                               const float* __restrict__ R,
                                               unsigned short* __restrict__ w2,
                                               unsigned short* __restrict__ w0f,
                                               unsigned short* __restrict__ biasC) {
    if (blockIdx.x < 32768) {
        // biasC in MFMA C-fragment order (key-permuted; see R3 comment)
        int gidx = blockIdx.x * 256 + threadIdx.x;       // [0, 8388608)
        int lane = gidx & 255, tjv = (gidx >> 8) & 63, ti = (gidx >> 14) & 63, h = gidx >> 20;
        int q = lane >> 4, n = lane & 15;
        int j = 64 * (tjv >> 2) + 4 * n + (tjv & 3);
        int jx = j >> 5, jy = j & 31;
        const float* Rh = R + (h << 10);
        unsigned short v[4];
        for (int r = 0; r < 4; ++r) {
            int i = 16 * ti + 4 * q + r;
            int ix = i >> 5, iy = i & 31;
            float val = Rh[(((ix - jx) & 31) << 5) + ((iy - jy) & 31)] * SCL;
            v[r] = f2bf(val);
        }
        unsigned long long pk = (unsigned long long)v[0] | ((unsigned long long)v[1] << 16) |
                                ((unsigned long long)v[2] << 32) | ((unsigned long long)v[3] << 48);
        *(unsigned long long*)&biasC[(size_t)gidx * 4] = pk;
    } else {
        int idx = (blockIdx.x - 32768) * 256 + threadIdx.x;  // [0, 262144)
        if (idx < 196608) {
            // wqkv rows 0-511 Wq*SCL, 512-1023 Wk, 1024-1535 Wv -> frag order
            int row = idx >> 7, col = idx & 127;
            float v;
            if (row < 512)       v = Wq[idx] * SCL;
            else if (row < 1024) v = Wk[idx - 65536];
            else                 v = Wv[idx - 131072];
            int rt = row >> 4, nr = row & 15, kc = col >> 5, qc = (col & 31) >> 3, jc = col & 7;
            w2[((rt * 4 + kc) * 512) + (qc * 16 + nr) * 8 + jc] = f2bf(v);
        } else {
            // W0 (c, hd) -> frag order over (ct=c/16, kcA=hd/32)
            int idx2 = idx - 196608;
            int row = idx2 >> 9, col = idx2 & 511;
            int rt = row >> 4, nr = row & 15, kcA = col >> 5, qc = (col & 31) >> 3, jc = col & 7;
            w0f[((rt * 16 + kcA) * 512) + (qc * 16 + nr) * 8 + jc] = f2bf(W0[idx2]);
        }
    }
}

// xt2: x transposed+scaled, in B/A fragment order over (b, pt=pos/16, kc=c/32).
__global__ __launch_bounds__(256) void prep_xt(const float* __restrict__ x,
                                               unsigned short* __restrict__ xt2) {
    __shared__ float lds[64 * 65];
    int b = blockIdx.x, c0 = blockIdx.y * 64, p0 = blockIdx.z * 64;
    int t = threadIdx.x, tr = t >> 6, tc = t & 63;
    const float inv_layer = 0.44721359549995793f;  // 1/sqrt(5)
    for (int rr = 0; rr < 16; ++rr) {
        int cl = rr * 4 + tr;
        lds[cl * 65 + tc] = x[(b * CIN + c0 + cl) * SEQ + p0 + tc];
    }
    __syncthreads();
    for (int rr = 0; rr < 16; ++rr) {
        int pl = rr * 4 + tr;
        int pos = p0 + pl, c = c0 + tc;
        int pt = pos >> 4, np = pos & 15, kc = c >> 5, qc = (c & 31) >> 3, jc = c & 7;
        xt2[((size_t)((b * 64 + pt) * 4 + kc) * 512) + (qc * 16 + np) * 8 + jc] =
            f2bf(lds[tc * 65 + pl] * inv_layer);
    }
}

// ---------------- fused QKV projection ----------------
// y in [0,16): Q/K, A = wqkv rows (m=wrow), B = xt (n=pos). D row = wrow.
//   Q (y<8)  -> natural (b,h,pos,d), 8B packed stores.
//   K (y>=8) -> Kf fragment order (8B scatter, key-permutation folded in).
// y in [16,24): V, A = xt (m=pos), B = Wv rows (n=vrow). D row = pos.
//   -> Vf fragment order (8B scatter).
__global__ __launch_bounds__(256, 4) void qkv_gemm(const unsigned short* __restrict__ xt2,
                                                   const unsigned short* __restrict__ w2,
                                                   unsigned short* __restrict__ Qt,
                                                   unsigned short* __restrict__ Kf,
                                                   unsigned short* __restrict__ Vf) {
    int b = blockIdx.x, y = blockIdx.y, zt = blockIdx.z;
    int tid = threadIdx.x, wave = tid >> 6, lane = tid & 63, q = lane >> 4, n = lane & 15;
    floatx4 acc[4];
    for (int s = 0; s < 4; ++s) acc[s] = (floatx4){0.f, 0.f, 0.f, 0.f};
    bf16x8 af[4], bfr[4][4];
    if (y < 16) {
        int rt = y * 4 + wave;                       // wrow tile
        const unsigned short* wbase = w2 + (size_t)rt * 4 * 512 + lane * 8;
        const unsigned short* xbase = xt2 + (size_t)(b * 64 + zt * 4) * 4 * 512 + lane * 8;
        for (int kc = 0; kc < 4; ++kc) af[kc] = ldfrag(wbase + kc * 512);
        for (int s = 0; s < 4; ++s)
            for (int kc = 0; kc < 4; ++kc) bfr[s][kc] = ldfrag(xbase + (s * 4 + kc) * 512);
        for (int kc = 0; kc < 4; ++kc)
            for (int s = 0; s < 4; ++s)
                acc[s] = __builtin_amdgcn_mfma_f32_16x16x32_bf16(af[kc], bfr[s][kc], acc[s], 0, 0, 0);
        int wrow0 = y * 64 + wave * 16;
        int pos0 = zt * 64;
        int d0 = (wrow0 & 63) + 4 * q;
        if (y < 8) {
            int h = wrow0 >> 6;
            for (int s = 0; s < 4; ++s) {
                uint2 pk;
                pk.x = pkbf(acc[s][0], acc[s][1]);
                pk.y = pkbf(acc[s][2], acc[s][3]);
                int pos = pos0 + 16 * s + n;
                *(uint2*)&Qt[((size_t)(b * NH + h) * SEQ + pos) * DKH + d0] = pk;
            }
        } else {
            int h = (wrow0 >> 6) - 8;
            int bh = b * NH + h;
            int cd = d0 >> 5, qd = (d0 >> 3) & 3, j0 = d0 & 7;
            for (int s = 0; s < 4; ++s) {
                uint2 pk;
                pk.x = pkbf(acc[s][0], acc[s][1]);
                pk.y = pkbf(acc[s][2], acc[s][3]);
                int sk = n & 3, nk = 4 * s + (n >> 2);   // key 16s+n -> (sk, nk)
                size_t addr = ((size_t)(bh * 16 + zt) * 8 + sk * 2 + cd) * 512
                              + (qd * 16 + nk) * 8 + j0;
                *(uint2*)&Kf[addr] = pk;
            }
        }
    } else {
        int pt = zt * 4 + wave;                      // pos tile
        const unsigned short* xbase = xt2 + (size_t)((b * 64 + pt) * 4) * 512 + lane * 8;
        int rtv0 = 64 + (y - 16) * 4;                // V wrow tiles start at row 1024
        const unsigned short* wbase = w2 + (size_t)rtv0 * 4 * 512 + lane * 8;
        for (int kc = 0; kc < 4; ++kc) af[kc] = ldfrag(xbase + kc * 512);
        for (int s = 0; s < 4; ++s)
            for (int kc = 0; kc < 4; ++kc) bfr[s][kc] = ldfrag(wbase + (s * 4 + kc) * 512);
        for (int kc = 0; kc < 4; ++kc)
            for (int s = 0; s < 4; ++s)
                acc[s] = __builtin_amdgcn_mfma_f32_16x16x32_bf16(af[kc], bfr[s][kc], acc[s], 0, 0, 0);
        int vrow0 = (y - 16) * 64;
        int jl = wave * 16 + 4 * q;                  // local j within the 64-tile
        int cj = jl >> 5, qj = (jl >> 3) & 3, jj0 = jl & 7;
        for (int s = 0; s < 4; ++s) {
            int vrow = vrow0 + 16 * s + n;
            int h = vrow >> 6, d = vrow & 63;
            int u = d >> 4, nl = d & 15;
            uint2 pk;
            pk.x = pkbf(acc[s][0], acc[s][1]);
            pk.y = pkbf(acc[s][2], acc[s][3]);
            size_t addr = ((size_t)((b * NH + h) * 16 + zt) * 8 + u * 2 + cj) * 512
                          + (qj * 16 + nl) * 8 + jj0;
            *(uint2*)&Vf[addr] = pk;
        }
    }
}

// ---------------- attention (barrier-free, fragment-direct K/V) ----------------
// WG = 128 queries (4 waves x 32); key tiles of 64; grid swizzle: gid&255 =
// (b,h) so each XCD sees one head (L2-resident bias/Kf/Vf). All 4 waves load
// identical Kf/Vf lines per kt -> L1 broadcast. LDS = per-wave P only.
__global__ __launch_bounds__(256, 3) void attn_kernel(const unsigned short* __restrict__ Qt,
                                                      const unsigned short* __restrict__ Kf,
                                                      const unsigned short* __restrict__ Vf,
                                                      const unsigned short* __restrict__ biasC,
                                                      unsigned short* __restrict__ att2) {
    __shared__ alignas(16) unsigned short lds_p[4][32 * 72]; // per-wave P (i, actual j)

    int gid = blockIdx.x;
    int bh = gid & 255, qb = gid >> 8;
    int b = bh >> 3, h = bh & 7;
    int tid = threadIdx.x, wave = tid >> 6, lane = tid & 63, q = lane >> 4, n = lane & 15;
    int i0 = qb * 128 + wave * 32;

    const unsigned short* qbase = Qt + (size_t)bh * SEQ * DKH;
    const unsigned short* kfb = Kf + (size_t)bh * 16 * 8 * 512 + lane * 8;
    const unsigned short* vfb = Vf + (size_t)bh * 16 * 8 * 512 + lane * 8;
    const unsigned short* bCh = biasC + (size_t)h * 64 * 64 * 1024;

    bf16x8 aq[2][2];
    for (int mt = 0; mt < 2; ++mt)
        for (int c = 0; c < 2; ++c)
            aq[mt][c] = ldfrag(qbase + (i0 + mt * 16 + n) * DKH + c * 32 + q * 8);

    // all-ones B fragment for row-sum MFMA (l = P @ 1)
    u16x8 ones_u;
    for (int t = 0; t < 8; ++t) ones_u[t] = 0x3F80;
    bf16x8 vone = __builtin_bit_cast(bf16x8, ones_u);

    floatx4 o[2][4], acc_l[2];
    for (int mt = 0; mt < 2; ++mt) {
        acc_l[mt] = (floatx4){0.f, 0.f, 0.f, 0.f};
        for (int u = 0; u < 4; ++u) o[mt][u] = (floatx4){0.f, 0.f, 0.f, 0.f};
    }

    unsigned short* pw = &lds_p[wave][0];
    int ti0 = i0 >> 4;

    for (int kt = 0; kt < 16; ++kt) {
        const unsigned short* kfp = kfb + (size_t)kt * 8 * 512;
        const unsigned short* vfp = vfb + (size_t)kt * 8 * 512;

        // issue all global loads up front (bias, K-frags, V-frags)
        uint2 bld[2][4];
        for (int mt = 0; mt < 2; ++mt)
            for (int s = 0; s < 4; ++s)
                bld[mt][s] = *(const uint2*)(bCh + ((size_t)((ti0 + mt) * 64 + 4 * kt + s) * 1024) + lane * 4);
        bf16x8 kf2[4][2];
        for (int s = 0; s < 4; ++s)
            for (int c = 0; c < 2; ++c) kf2[s][c] = ldfrag(kfp + (s * 2 + c) * 512);
        bf16x8 vf2[4][2];
        for (int u = 0; u < 4; ++u)
            for (int c = 0; c < 2; ++c) vf2[u][c] = ldfrag(vfp + (u * 2 + c) * 512);

        // S = Q K^T + bias (C-init); virtual col 16s+n = actual key 4n+s
        floatx4 sv[2][4];
        for (int mt = 0; mt < 2; ++mt)
            for (int s = 0; s < 4; ++s)
                sv[mt][s] = (floatx4){bfhi(bld[mt][s].x), bflo(bld[mt][s].x),
                                      bfhi(bld[mt][s].y), bflo(bld[mt][s].y)};
        for (int s = 0; s < 4; ++s)
            for (int mt = 0; mt < 2; ++mt) {
                sv[mt][s] = __builtin_amdgcn_mfma_f32_16x16x32_bf16(aq[mt][0], kf2[s][0], sv[mt][s], 0, 0, 0);
                sv[mt][s] = __builtin_amdgcn_mfma_f32_16x16x32_bf16(aq[mt][1], kf2[s][1], sv[mt][s], 0, 0, 0);
            }

        // P = exp2(S); pack adjacent actual keys (4n..4n+3) via v_perm; b64 store
        for (int mt = 0; mt < 2; ++mt)
            for (int r = 0; r < 4; ++r) {
                unsigned int p0 = __builtin_bit_cast(unsigned int, __builtin_amdgcn_exp2f(sv[mt][0][r]));
                unsigned int p1 = __builtin_bit_cast(unsigned int, __builtin_amdgcn_exp2f(sv[mt][1][r]));
                unsigned int p2 = __builtin_bit_cast(unsigned int, __builtin_amdgcn_exp2f(sv[mt][2][r]));
                unsigned int p3 = __builtin_bit_cast(unsigned int, __builtin_amdgcn_exp2f(sv[mt][3][r]));
                uint2 pk;
                pk.x = __builtin_amdgcn_perm(p1, p0, 0x07060302u);  // [hi(p0), hi(p1)]
                pk.y = __builtin_amdgcn_perm(p3, p2, 0x07060302u);  // [hi(p2), hi(p3)]
                *(uint2*)&pw[(mt * 16 + 4 * q + r) * 72 + 4 * n] = pk;
            }
        // no barrier anywhere: lds_p is per-wave, DS ops are wave-ordered

        // O += P V ; l += P @ 1 (row sums on the MFMA pipe)
        bf16x8 ap[2][2];
        for (int mt = 0; mt < 2; ++mt)
            for (int c = 0; c < 2; ++c)
                ap[mt][c] = ldfrag(&pw[(mt * 16 + n) * 72 + c * 32 + q * 8]);
        for (int mt = 0; mt < 2; ++mt) {
            acc_l[mt] = __builtin_amdgcn_mfma_f32_16x16x32_bf16(ap[mt][0], vone, acc_l[mt], 0, 0, 0);
            acc_l[mt] = __builtin_amdgcn_mfma_f32_16x16x32_bf16(ap[mt][1], vone, acc_l[mt], 0, 0, 0);
        }
        for (int u = 0; u < 4; ++u)
            for (int mt = 0; mt < 2; ++mt) {
                o[mt][u] = __builtin_amdgcn_mfma_f32_16x16x32_bf16(ap[mt][0], vf2[u][0], o[mt][u], 0, 0, 0);
                o[mt][u] = __builtin_amdgcn_mfma_f32_16x16x32_bf16(ap[mt][1], vf2[u][1], o[mt][u], 0, 0, 0);
            }
    }

    // epilogue: write att2 in A-fragment order (pos=i0+mt*16+4q+r, hd=h*64+16u+n)
    for (int mt = 0; mt < 2; ++mt)
        for (int r = 0; r < 4; ++r) {
            float inv = 1.0f / acc_l[mt][r];
            int pt = (i0 >> 4) + mt;
            int np = 4 * q + r;
            for (int u = 0; u < 4; ++u) {
                int kcA = 2 * h + (u >> 1);
                int kq = 2 * (u & 1) + (n >> 3);
                att2[((size_t)((b * 64 + pt) * 16 + kcA) * 512) + (kq * 16 + np) * 8 + (n & 7)] =
                    f2bf(o[mt][u][r] * inv);
            }
        }
}

// ---------------- output projection + residual ----------------
// A = att2 (m=pos), B = w0f (n=c); K=512 in 4 hoisted groups of 4 kcA.
// D row = pos -> float4 stores + float4 residual loads.
__global__ __launch_bounds__(256, 4) void out_gemm(const unsigned short* __restrict__ att2,
                                                   const unsigned short* __restrict__ w0f,
                                                   const float* __restrict__ x,
                                                   float* __restrict__ out) {
    int b = blockIdx.x, ct = blockIdx.y, ptb = blockIdx.z;
    int tid = threadIdx.x, wave = tid >> 6, lane = tid & 63, q = lane >> 4, n = lane & 15;
    int pos0 = ptb * 64 + wave * 16;
    int c0 = ct * 64;
    int pt = ptb * 4 + wave;
    const unsigned short* abase = att2 + (size_t)(b * 64 + pt) * 16 * 512 + lane * 8;
    const unsigned short* wbase = w0f + (size_t)(c0 >> 4) * 16 * 512 + lane * 8;
    floatx4 acc[4];
    for (int s = 0; s < 4; ++s) acc[s] = (floatx4){0.f, 0.f, 0.f, 0.f};
    for (int g = 0; g < 4; ++g) {
        bf16x8 af[4], bfr[4][4];
        for (int k2 = 0; k2 < 4; ++k2) af[k2] = ldfrag(abase + (g * 4 + k2) * 512);
        for (int s = 0; s < 4; ++s)
            for (int k2 = 0; k2 < 4; ++k2)
                bfr[s][k2] = ldfrag(wbase + (s * 16 + g * 4 + k2) * 512);
        for (int k2 = 0; k2 < 4; ++k2)
            for (int s = 0; s < 4; ++s)
                acc[s] = __builtin_amdgcn_mfma_f32_16x16x32_bf16(af[k2], bfr[s][k2], acc[s], 0, 0, 0);
    }
    int p0q = pos0 + 4 * q;
    for (int s = 0; s < 4; ++s) {
        int c = c0 + 16 * s + n;
        size_t idx = ((size_t)b * CIN + c) * SEQ + p0q;
        floatx4 res = *(const floatx4*)&x[idx];
        floatx4 v = acc[s] + res;
        *(floatx4*)&out[idx] = v;
    }
}

// ---------------- launch ----------------
extern "C" void kernel_launch(void* const* d_in, const int* in_sizes, int n_in,
                              void* d_out, int out_size, void* d_ws, size_t ws_size,
                              hipStream_t stream) {
    const float* x  = (const float*)d_in[0];
    const float* Wq = (const float*)d_in[1];
    const float* Wk = (const float*)d_in[2];
    const float* Wv = (const float*)d_in[3];
    const float* R  = (const float*)d_in[4];
    const float* W0 = (const float*)d_in[5];
    float* out = (float*)d_out;

    char* ws = (char*)d_ws;
    size_t off = 0;
    unsigned short* Qt   = (unsigned short*)(ws + off); off += (size_t)NB * NH * SEQ * DKH * 2;
    unsigned short* Kf   = (unsigned short*)(ws + off); off += (size_t)NB * NH * SEQ * DKH * 2;
    unsigned short* Vf   = (unsigned short*)(ws + off); off += (size_t)NB * NH * SEQ * DKH * 2;
    unsigned short* att2 = (unsigned short*)(ws + off); off += (size_t)NB * SEQ * HDIM * 2;
    unsigned short* xt2  = (unsigned short*)(ws + off); off += (size_t)NB * SEQ * CIN * 2;
    unsigned short* w2   = (unsigned short*)(ws + off); off += (size_t)1536 * 128 * 2;
    unsigned short* w0f  = (unsigned short*)(ws + off); off += (size_t)128 * 512 * 2;
    unsigned short* biasC= (unsigned short*)(ws + off); off += (size_t)NH * SEQ * SEQ * 2;
    (void)ws_size; (void)in_sizes; (void)n_in; (void)out_size;

    prep_wb<<<33792, 256, 0, stream>>>(Wq, Wk, Wv, W0, R, w2, w0f, biasC);
    prep_xt<<<dim3(NB, 2, 16), 256, 0, stream>>>(x, xt2);
    qkv_gemm<<<dim3(NB, 24, 16), 256, 0, stream>>>(xt2, w2, Qt, Kf, Vf);
    attn_kernel<<<NB * NH * 8, 256, 0, stream>>>(Qt, Kf, Vf, biasC, att2);
    out_gemm<<<dim3(NB, 2, 16), 256, 0, stream>>>(att2, w0f, x, out);
}

// Round 7
// 256.978 us; speedup vs baseline: 1.3180x; 1.3180x over previous
//
#include <hip/hip_runtime.h>

// CvT block, MI355X bf16-MFMA implementation.
// B=32, C=128, L=32 (seq=1024), H=8, DK=64, HD=512, NLAYER=4.
// R7: attn = R5 LDS-staged structure, but (a) K/V staged from global
// fragment-packed Kf/Vf via contiguous b128 copies with register prefetch
// of tile kt+1 (R6's global-direct was latency-bound, VGPR=68 sank loads);
// (b) 64 queries/wave (WG=256q) halves per-query K/V LDS fragment reads
// and staging; (c) biasC compacted 4x.

#define NB   32
#define NH   8
#define SEQ  1024
#define DKH  64
#define HDIM 512
#define CIN  128

// 0.125 * log2(e): folded into Wq and bias so scores are in exp2 domain.
#define SCL 0.18033688011112042f

typedef __bf16 bf16x8 __attribute__((ext_vector_type(8)));
typedef float floatx4 __attribute__((ext_vector_type(4)));
typedef unsigned short u16x8 __attribute__((ext_vector_type(8)));

__device__ __forceinline__ unsigned short f2bf(float f) {
    union { float f; unsigned int u; } c; c.f = f;
    unsigned int u = c.u;
    return (unsigned short)((u + 0x7fffu + ((u >> 16) & 1u)) >> 16); // RNE
}
__device__ __forceinline__ bf16x8 ldfrag(const unsigned short* p) {
    u16x8 v = *reinterpret_cast<const u16x8*>(p);
    return __builtin_bit_cast(bf16x8, v);
}
__device__ __forceinline__ float bfhi(unsigned int u) {  // low short -> f32
    return __builtin_bit_cast(float, u << 16);
}
__device__ __forceinline__ float bflo(unsigned int u) {  // high short -> f32
    return __builtin_bit_cast(float, u & 0xFFFF0000u);
}
// pack two f32 -> two RNE bf16; 'a' lands in the LOW short.
__device__ __forceinline__ unsigned int pkbf(float a, float b) {
    unsigned int ua = __builtin_bit_cast(unsigned int, a);
    unsigned int ub = __builtin_bit_cast(unsigned int, b);
    ua += 0x7fffu + ((ua >> 16) & 1u);
    ub += 0x7fffu + ((ub >> 16) & 1u);
    return __builtin_amdgcn_perm(ub, ua, 0x07060302u);
}

// Fragment-order storage: a 512-elem block holds one wave B/A fragment,
// [lane=q*16+n][j=0..7]; a wave's fragment load = base + lane*8 = 1KB burst.
// Kf: frag (s,c) lane (q,n) j  <->  K[key = 4n+s (permuted)][d = 32c+8q+j]
//     Kf[((bh*16+kt)*8 + s*2+c)*512 + lane*8 + j]   (tile = 8KB contiguous)
// Vf: frag (u,c) lane (q,n) j  <->  V[d = 16u+n][j_local = 32c+8q+j]

// ---------------- prep: weights + swizzled bias ----------------
// blocks [0, 8192): biasC compact C-fragment order: slot = (h*64+ti)*64+tjv,
//   biasC[slot*256 + lane*4 + r], lane in [0,64): value for
//   (row 16ti+4q+r, virtual col 16s+n) with j = 64*(tjv>>2)+4n+(tjv&3).
// blocks [8192, 9216): weight casts; Wq scaled by SCL (exp2 domain).
__global__ __launch_bounds__(256) void prep_wb(const float* __restrict__ Wq,
                                               const float* __restrict__ Wk,
                                               const float* __restrict__ Wv,
                                               const float* __restrict__ W0,
                                               const float* __restrict__ R,
                                               unsigned short* __restrict__ w2,
                                               unsigned short* __restrict__ w0f,
                                               unsigned short* __restrict__ biasC) {
    if (blockIdx.x < 8192) {
        int gidx = blockIdx.x * 256 + threadIdx.x;       // [0, 2097152)
        int lane = gidx & 63, slot = gidx >> 6;          // slot in [0, 32768)
        int tjv = slot & 63, ti = (slot >> 6) & 63, h = slot >> 12;
        int q = lane >> 4, n = lane & 15;
        int j = 64 * (tjv >> 2) + 4 * n + (tjv & 3);
        int jx = j >> 5, jy = j & 31;
        const float* Rh = R + (h << 10);
        unsigned short v[4];
        for (int r = 0; r < 4; ++r) {
            int i = 16 * ti + 4 * q + r;
            int ix = i >> 5, iy = i & 31;
            float val = Rh[(((ix - jx) & 31) << 5) + ((iy - jy) & 31)] * SCL;
            v[r] = f2bf(val);
        }
        unsigned long long pk = (unsigned long long)v[0] | ((unsigned long long)v[1] << 16) |
                                ((unsigned long long)v[2] << 32) | ((unsigned long long)v[3] << 48);
        *(unsigned long long*)&biasC[(size_t)gidx * 4] = pk;
    } else {
        int idx = (blockIdx.x - 8192) * 256 + threadIdx.x;  // [0, 262144)
        if (idx < 196608) {
            int row = idx >> 7, col = idx & 127;
            float v;
            if (row < 512)       v = Wq[idx] * SCL;
            else if (row < 1024) v = Wk[idx - 65536];
            else                 v = Wv[idx - 131072];
            int rt = row >> 4, nr = row & 15, kc = col >> 5, qc = (col & 31) >> 3, jc = col & 7;
            w2[((rt * 4 + kc) * 512) + (qc * 16 + nr) * 8 + jc] = f2bf(v);
        } else {
            int idx2 = idx - 196608;
            int row = idx2 >> 9, col = idx2 & 511;
            int rt = row >> 4, nr = row & 15, kcA = col >> 5, qc = (col & 31) >> 3, jc = col & 7;
            w0f[((rt * 16 + kcA) * 512) + (qc * 16 + nr) * 8 + jc] = f2bf(W0[idx2]);
        }
    }
}

// xt2: x transposed+scaled, in B/A fragment order over (b, pt=pos/16, kc=c/32).
__global__ __launch_bounds__(256) void prep_xt(const float* __restrict__ x,
                                               unsigned short* __restrict__ xt2) {
    __shared__ float lds[64 * 65];
    int b = blockIdx.x, c0 = blockIdx.y * 64, p0 = blockIdx.z * 64;
    int t = threadIdx.x, tr = t >> 6, tc = t & 63;
    const float inv_layer = 0.44721359549995793f;  // 1/sqrt(5)
    for (int rr = 0; rr < 16; ++rr) {
        int cl = rr * 4 + tr;
        lds[cl * 65 + tc] = x[(b * CIN + c0 + cl) * SEQ + p0 + tc];
    }
    __syncthreads();
    for (int rr = 0; rr < 16; ++rr) {
        int pl = rr * 4 + tr;
        int pos = p0 + pl, c = c0 + tc;
        int pt = pos >> 4, np = pos & 15, kc = c >> 5, qc = (c & 31) >> 3, jc = c & 7;
        xt2[((size_t)((b * 64 + pt) * 4 + kc) * 512) + (qc * 16 + np) * 8 + jc] =
            f2bf(lds[tc * 65 + pl] * inv_layer);
    }
}

// ---------------- fused QKV projection ----------------
// y in [0,16): Q/K, A = wqkv rows (m=wrow), B = xt (n=pos). D row = wrow.
//   Q (y<8)  -> natural (b,h,pos,d), 8B packed stores.
//   K (y>=8) -> Kf fragment order (8B scatter, key-permutation folded in).
// y in [16,24): V, A = xt (m=pos), B = Wv rows (n=vrow). D row = pos.
//   -> Vf fragment order (8B scatter).
__global__ __launch_bounds__(256, 4) void qkv_gemm(const unsigned short* __restrict__ xt2,
                                                   const unsigned short* __restrict__ w2,
                                                   unsigned short* __restrict__ Qt,
                                                   unsigned short* __restrict__ Kf,
                                                   unsigned short* __restrict__ Vf) {
    int b = blockIdx.x, y = blockIdx.y, zt = blockIdx.z;
    int tid = threadIdx.x, wave = tid >> 6, lane = tid & 63, q = lane >> 4, n = lane & 15;
    floatx4 acc[4];
    for (int s = 0; s < 4; ++s) acc[s] = (floatx4){0.f, 0.f, 0.f, 0.f};
    bf16x8 af[4], bfr[4][4];
    if (y < 16) {
        int rt = y * 4 + wave;                       // wrow tile
        const unsigned short* wbase = w2 + (size_t)rt * 4 * 512 + lane * 8;
        const unsigned short* xbase = xt2 + (size_t)(b * 64 + zt * 4) * 4 * 512 + lane * 8;
        for (int kc = 0; kc < 4; ++kc) af[kc] = ldfrag(wbase + kc * 512);
        for (int s = 0; s < 4; ++s)
            for (int kc = 0; kc < 4; ++kc) bfr[s][kc] = ldfrag(xbase + (s * 4 + kc) * 512);
        for (int kc = 0; kc < 4; ++kc)
            for (int s = 0; s < 4; ++s)
                acc[s] = __builtin_amdgcn_mfma_f32_16x16x32_bf16(af[kc], bfr[s][kc], acc[s], 0, 0, 0);
        int wrow0 = y * 64 + wave * 16;
        int pos0 = zt * 64;
        int d0 = (wrow0 & 63) + 4 * q;
        if (y < 8) {
            int h = wrow0 >> 6;
            for (int s = 0; s < 4; ++s) {
                uint2 pk;
                pk.x = pkbf(acc[s][0], acc[s][1]);
                pk.y = pkbf(acc[s][2], acc[s][3]);
                int pos = pos0 + 16 * s + n;
                *(uint2*)&Qt[((size_t)(b * NH + h) * SEQ + pos) * DKH + d0] = pk;
            }
        } else {
            int h = (wrow0 >> 6) - 8;
            int bh = b * NH + h;
            int cd = d0 >> 5, qd = (d0 >> 3) & 3, j0 = d0 & 7;
            for (int s = 0; s < 4; ++s) {
                uint2 pk;
                pk.x = pkbf(acc[s][0], acc[s][1]);
                pk.y = pkbf(acc[s][2], acc[s][3]);
                int sk = n & 3, nk = 4 * s + (n >> 2);   // key 16s+n -> (sk, nk)
                size_t addr = ((size_t)(bh * 16 + zt) * 8 + sk * 2 + cd) * 512
                              + (qd * 16 + nk) * 8 + j0;
                *(uint2*)&Kf[addr] = pk;
            }
        }
    } else {
        int pt = zt * 4 + wave;                      // pos tile
        const unsigned short* xbase = xt2 + (size_t)((b * 64 + pt) * 4) * 512 + lane * 8;
        int rtv0 = 64 + (y - 16) * 4;                // V wrow tiles start at row 1024
        const unsigned short* wbase = w2 + (size_t)rtv0 * 4 * 512 + lane * 8;
        for (int kc = 0; kc < 4; ++kc) af[kc] = ldfrag(xbase + kc * 512);
        for (int s = 0; s < 4; ++s)
            for (int kc = 0; kc < 4; ++kc) bfr[s][kc] = ldfrag(wbase + (s * 4 + kc) * 512);
        for (int kc = 0; kc < 4; ++kc)
            for (int s = 0; s < 4; ++s)
                acc[s] = __builtin_amdgcn_mfma_f32_16x16x32_bf16(af[kc], bfr[s][kc], acc[s], 0, 0, 0);
        int vrow0 = (y - 16) * 64;
        int jl = wave * 16 + 4 * q;                  // local j within the 64-tile
        int cj = jl >> 5, qj = (jl >> 3) & 3, jj0 = jl & 7;
        for (int s = 0; s < 4; ++s) {
            int vrow = vrow0 + 16 * s + n;
            int h = vrow >> 6, d = vrow & 63;
            int u = d >> 4, nl = d & 15;
            uint2 pk;
            pk.x = pkbf(acc[s][0], acc[s][1]);
            pk.y = pkbf(acc[s][2], acc[s][3]);
            size_t addr = ((size_t)((b * NH + h) * 16 + zt) * 8 + u * 2 + cj) * 512
                          + (qj * 16 + nl) * 8 + jj0;
            *(uint2*)&Vf[addr] = pk;
        }
    }
}

// ---------------- attention ----------------
// WG = 256 queries (4 waves x 64); key tiles of 64; grid swizzle: gid&255 =
// (b,h) -> one head per XCD. K/V tiles staged LDS from fragment-packed
// global (contiguous 8KB) with register prefetch of tile kt+1.
__global__ __launch_bounds__(256, 2) void attn_kernel(const unsigned short* __restrict__ Qt,
                                                      const unsigned short* __restrict__ Kf,
                                                      const unsigned short* __restrict__ Vf,
                                                      const unsigned short* __restrict__ biasC,
                                                      unsigned short* __restrict__ att2) {
    __shared__ alignas(16) unsigned short lds_k[8 * 512];    // frag-packed K tile
    __shared__ alignas(16) unsigned short lds_v[8 * 512];    // frag-packed V tile
    __shared__ alignas(16) unsigned short lds_p[4][64 * 72]; // per-wave P (i, actual j)

    int gid = blockIdx.x;
    int bh = gid & 255, qb = gid >> 8;
    int b = bh >> 3, h = bh & 7;
    int tid = threadIdx.x, wave = tid >> 6, lane = tid & 63, q = lane >> 4, n = lane & 15;
    int i0 = qb * 256 + wave * 64;
    int ti0 = i0 >> 4;

    const unsigned short* qbase = Qt + (size_t)bh * SEQ * DKH;
    const unsigned short* kft = Kf + (size_t)bh * 16 * 4096;
    const unsigned short* vft = Vf + (size_t)bh * 16 * 4096;
    const unsigned short* bCh = biasC + (size_t)h * 64 * 64 * 256;

    bf16x8 aq[4][2];
    for (int mt = 0; mt < 4; ++mt)
        for (int c = 0; c < 2; ++c)
            aq[mt][c] = ldfrag(qbase + (i0 + mt * 16 + n) * DKH + c * 32 + q * 8);

    // all-ones B fragment for row-sum MFMA (l = P @ 1)
    u16x8 ones_u;
    for (int t = 0; t < 8; ++t) ones_u[t] = 0x3F80;
    bf16x8 vone = __builtin_bit_cast(bf16x8, ones_u);

    floatx4 o[4][4], acc_l[4];
    for (int mt = 0; mt < 4; ++mt) {
        acc_l[mt] = (floatx4){0.f, 0.f, 0.f, 0.f};
        for (int u = 0; u < 4; ++u) o[mt][u] = (floatx4){0.f, 0.f, 0.f, 0.f};
    }

    unsigned short* pw = &lds_p[wave][0];

    // register prefetch of tile 0
    u16x8 kpre0, kpre1, vpre0, vpre1;
    {
        const unsigned short* kp = kft + tid * 16;
        const unsigned short* vp = vft + tid * 16;
        kpre0 = *(const u16x8*)kp;  kpre1 = *(const u16x8*)(kp + 8);
        vpre0 = *(const u16x8*)vp;  vpre1 = *(const u16x8*)(vp + 8);
    }

    for (int kt = 0; kt < 16; ++kt) {
        __syncthreads();  // prior iter's LDS reads done
        *(u16x8*)&lds_k[tid * 16]     = kpre0;
        *(u16x8*)&lds_k[tid * 16 + 8] = kpre1;
        *(u16x8*)&lds_v[tid * 16]     = vpre0;
        *(u16x8*)&lds_v[tid * 16 + 8] = vpre1;
        __syncthreads();
        if (kt < 15) {  // prefetch next tile; latency hidden behind compute
            const unsigned short* kp = kft + (kt + 1) * 4096 + tid * 16;
            const unsigned short* vp = vft + (kt + 1) * 4096 + tid * 16;
            kpre0 = *(const u16x8*)kp;  kpre1 = *(const u16x8*)(kp + 8);
            vpre0 = *(const u16x8*)vp;  vpre1 = *(const u16x8*)(vp + 8);
        }

        // K fragments (shared across the 4 mt tiles)
        bf16x8 kf2[4][2];
        for (int s = 0; s < 4; ++s)
            for (int c = 0; c < 2; ++c)
                kf2[s][c] = ldfrag(&lds_k[(s * 2 + c) * 512 + lane * 8]);

        // S = Q K^T + bias; P = exp2(S) -> per-wave LDS
        for (int mt = 0; mt < 4; ++mt) {
            uint2 bl[4];
            for (int s = 0; s < 4; ++s)
                bl[s] = *(const uint2*)(bCh + (((size_t)(ti0 + mt) * 64 + 4 * kt + s) << 8) + lane * 4);
            floatx4 sv[4];
            for (int s = 0; s < 4; ++s) {
                sv[s] = (floatx4){bfhi(bl[s].x), bflo(bl[s].x), bfhi(bl[s].y), bflo(bl[s].y)};
                sv[s] = __builtin_amdgcn_mfma_f32_16x16x32_bf16(aq[mt][0], kf2[s][0], sv[s], 0, 0, 0);
                sv[s] = __builtin_amdgcn_mfma_f32_16x16x32_bf16(aq[mt][1], kf2[s][1], sv[s], 0, 0, 0);
            }
            for (int r = 0; r < 4; ++r) {
                unsigned int p0 = __builtin_bit_cast(unsigned int, __builtin_amdgcn_exp2f(sv[0][r]));
                unsigned int p1 = __builtin_bit_cast(unsigned int, __builtin_amdgcn_exp2f(sv[1][r]));
                unsigned int p2 = __builtin_bit_cast(unsigned int, __builtin_amdgcn_exp2f(sv[2][r]));
                unsigned int p3 = __builtin_bit_cast(unsigned int, __builtin_amdgcn_exp2f(sv[3][r]));
                uint2 pk;
                pk.x = __builtin_amdgcn_perm(p1, p0, 0x07060302u);
                pk.y = __builtin_amdgcn_perm(p3, p2, 0x07060302u);
                *(uint2*)&pw[(mt * 16 + 4 * q + r) * 72 + 4 * n] = pk;
            }
        }
        // no barrier: lds_p is per-wave (in-wave DS ordering)

        // V fragments + P fragments, then O += P V, l += P @ 1
        bf16x8 vf2[4][2];
        for (int u = 0; u < 4; ++u)
            for (int c = 0; c < 2; ++c)
                vf2[u][c] = ldfrag(&lds_v[(u * 2 + c) * 512 + lane * 8]);
        bf16x8 ap[4][2];
        for (int mt = 0; mt < 4; ++mt)
            for (int c = 0; c < 2; ++c)
                ap[mt][c] = ldfrag(&pw[(mt * 16 + n) * 72 + c * 32 + q * 8]);
        for (int mt = 0; mt < 4; ++mt) {
            acc_l[mt] = __builtin_amdgcn_mfma_f32_16x16x32_bf16(ap[mt][0], vone, acc_l[mt], 0, 0, 0);
            acc_l[mt] = __builtin_amdgcn_mfma_f32_16x16x32_bf16(ap[mt][1], vone, acc_l[mt], 0, 0, 0);
        }
        for (int u = 0; u < 4; ++u)
            for (int mt = 0; mt < 4; ++mt) {
                o[mt][u] = __builtin_amdgcn_mfma_f32_16x16x32_bf16(ap[mt][0], vf2[u][0], o[mt][u], 0, 0, 0);
                o[mt][u] = __builtin_amdgcn_mfma_f32_16x16x32_bf16(ap[mt][1], vf2[u][1], o[mt][u], 0, 0, 0);
            }
    }

    // epilogue: att2 in A-fragment order (pos=i0+mt*16+4q+r, hd=h*64+16u+n)
    for (int mt = 0; mt < 4; ++mt)
        for (int r = 0; r < 4; ++r) {
            float inv = 1.0f / acc_l[mt][r];
            int pt = ti0 + mt;
            int np = 4 * q + r;
            for (int u = 0; u < 4; ++u) {
                int kcA = 2 * h + (u >> 1);
                int kq = 2 * (u & 1) + (n >> 3);
                att2[((size_t)((b * 64 + pt) * 16 + kcA) * 512) + (kq * 16 + np) * 8 + (n & 7)] =
                    f2bf(o[mt][u][r] * inv);
            }
        }
}

// ---------------- output projection + residual ----------------
// A = att2 (m=pos), B = w0f (n=c); K=512 in 4 hoisted groups of 4 kcA.
__global__ __launch_bounds__(256, 4) void out_gemm(const unsigned short* __restrict__ att2,
                                                   const unsigned short* __restrict__ w0f,
                                                   const float* __restrict__ x,
                                                   float* __restrict__ out) {
    int b = blockIdx.x, ct = blockIdx.y, ptb = blockIdx.z;
    int tid = threadIdx.x, wave = tid >> 6, lane = tid & 63, q = lane >> 4, n = lane & 15;
    int pos0 = ptb * 64 + wave * 16;
    int c0 = ct * 64;
    int pt = ptb * 4 + wave;
    const unsigned short* abase = att2 + (size_t)(b * 64 + pt) * 16 * 512 + lane * 8;
    const unsigned short* wbase = w0f + (size_t)(c0 >> 4) * 16 * 512 + lane * 8;
    floatx4 acc[4];
    for (int s = 0; s < 4; ++s) acc[s] = (floatx4){0.f, 0.f, 0.f, 0.f};
    for (int g = 0; g < 4; ++g) {
        bf16x8 af[4], bfr[4][4];
        for (int k2 = 0; k2 < 4; ++k2) af[k2] = ldfrag(abase + (g * 4 + k2) * 512);
        for (int s = 0; s < 4; ++s)
            for (int k2 = 0; k2 < 4; ++k2)
                bfr[s][k2] = ldfrag(wbase + (s * 16 + g * 4 + k2) * 512);
        for (int k2 = 0; k2 < 4; ++k2)
            for (int s = 0; s < 4; ++s)
                acc[s] = __builtin_amdgcn_mfma_f32_16x16x32_bf16(af[k2], bfr[s][k2], acc[s], 0, 0, 0);
    }
    int p0q = pos0 + 4 * q;
    for (int s = 0; s < 4; ++s) {
        int c = c0 + 16 * s + n;
        size_t idx = ((size_t)b * CIN + c) * SEQ + p0q;
        floatx4 res = *(const floatx4*)&x[idx];
        floatx4 v = acc[s] + res;
        *(floatx4*)&out[idx] = v;
    }
}

// ---------------- launch ----------------
extern "C" void kernel_launch(void* const* d_in, const int* in_sizes, int n_in,
                              void* d_out, int out_size, void* d_ws, size_t ws_size,
                              hipStream_t stream) {
    const float* x  = (const float*)d_in[0];
    const float* Wq = (const float*)d_in[1];
    const float* Wk = (const float*)d_in[2];
    const float* Wv = (const float*)d_in[3];
    const float* R  = (const float*)d_in[4];
    const float* W0 = (const float*)d_in[5];
    float* out = (float*)d_out;

    char* ws = (char*)d_ws;
    size_t off = 0;
    unsigned short* Qt   = (unsigned short*)(ws + off); off += (size_t)NB * NH * SEQ * DKH * 2;
    unsigned short* Kf   = (unsigned short*)(ws + off); off += (size_t)NB * NH * SEQ * DKH * 2;
    unsigned short* Vf   = (unsigned short*)(ws + off); off += (size_t)NB * NH * SEQ * DKH * 2;
    unsigned short* att2 = (unsigned short*)(ws + off); off += (size_t)NB * SEQ * HDIM * 2;
    unsigned short* xt2  = (unsigned short*)(ws + off); off += (size_t)NB * SEQ * CIN * 2;
    unsigned short* w2   = (unsigned short*)(ws + off); off += (size_t)1536 * 128 * 2;
    unsigned short* w0f  = (unsigned short*)(ws + off); off += (size_t)128 * 512 * 2;
    unsigned short* biasC= (unsigned short*)(ws + off); off += (size_t)NH * SEQ * SEQ * 2 / 4;
    (void)ws_size; (void)in_sizes; (void)n_in; (void)out_size;

    prep_wb<<<9216, 256, 0, stream>>>(Wq, Wk, Wv, W0, R, w2, w0f, biasC);
    prep_xt<<<dim3(NB, 2, 16), 256, 0, stream>>>(x, xt2);
    qkv_gemm<<<dim3(NB, 24, 16), 256, 0, stream>>>(xt2, w2, Qt, Kf, Vf);
    attn_kernel<<<NB * NH * 4, 256, 0, stream>>>(Qt, Kf, Vf, biasC, att2);
    out_gemm<<<dim3(NB, 2, 16), 256, 0, stream>>>(att2, w0f, x, out);
}

// Round 8
// 241.228 us; speedup vs baseline: 1.4040x; 1.0653x over previous
//
#include <hip/hip_runtime.h>

// CvT block, MI355X bf16-MFMA implementation.
// B=32, C=128, L=32 (seq=1024), H=8, DK=64, HD=512, NLAYER=4.
// R8: attention computed TRANSPOSED: S^T = K Q^T (m=key, n=query) so P^T
// stays in registers and feeds PV (O^T = V^T P^T) as a B-operand built by
// in-lane v_perm packing (slot jj <-> key 16(jj>>2)+4q+(jj&3); V stored
// with matching k-permutation). P never touches LDS: lds_p (36KB) and its
// round-trip deleted. l = ones-MFMA column sums. LDS = 16KB K/V tiles only.

#define NB   32
#define NH   8
#define SEQ  1024
#define DKH  64
#define HDIM 512
#define CIN  128

// 0.125 * log2(e): folded into Wq and bias so scores are in exp2 domain.
#define SCL 0.18033688011112042f

typedef __bf16 bf16x8 __attribute__((ext_vector_type(8)));
typedef float floatx4 __attribute__((ext_vector_type(4)));
typedef unsigned short u16x8 __attribute__((ext_vector_type(8)));
typedef unsigned int uintx4 __attribute__((ext_vector_type(4)));

__device__ __forceinline__ unsigned short f2bf(float f) {
    union { float f; unsigned int u; } c; c.f = f;
    unsigned int u = c.u;
    return (unsigned short)((u + 0x7fffu + ((u >> 16) & 1u)) >> 16); // RNE
}
__device__ __forceinline__ bf16x8 ldfrag(const unsigned short* p) {
    u16x8 v = *reinterpret_cast<const u16x8*>(p);
    return __builtin_bit_cast(bf16x8, v);
}
__device__ __forceinline__ float bfhi(unsigned int u) {  // low short -> f32
    return __builtin_bit_cast(float, u << 16);
}
__device__ __forceinline__ float bflo(unsigned int u) {  // high short -> f32
    return __builtin_bit_cast(float, u & 0xFFFF0000u);
}
// pack two f32 -> two RNE bf16; 'a' lands in the LOW short.
__device__ __forceinline__ unsigned int pkbf(float a, float b) {
    unsigned int ua = __builtin_bit_cast(unsigned int, a);
    unsigned int ub = __builtin_bit_cast(unsigned int, b);
    ua += 0x7fffu + ((ua >> 16) & 1u);
    ub += 0x7fffu + ((ub >> 16) & 1u);
    return __builtin_amdgcn_perm(ub, ua, 0x07060302u);
}

// Fragment-order storage: 512-elem block = one wave fragment [lane][j].
// Kf (A-frag, m=key): frag (s,c): lane (q,n) j <-> K[key=16s+n][d=32c+8q+j]
// Vf (A-frag, m=d, permuted k): frag (u,c): lane (q,n) jj <->
//     V[key = 32c+16(jj>>2)+4q+(jj&3)][d=16u+n]   (matches P^T pack order)

// ---------------- prep: weights + transposed bias ----------------
// blocks [0, 8192): biasT C-frag order for S^T: slot = (h*64+tq)*64+tjk,
//   biasT[slot*256 + lane*4 + r] = bias[query=16tq+n][key=16tjk+4q+r]*SCL.
// blocks [8192, 9216): weight casts; Wq scaled by SCL (exp2 domain).
__global__ __launch_bounds__(256) void prep_wb(const float* __restrict__ Wq,
                                               const float* __restrict__ Wk,
                                               const float* __restrict__ Wv,
                                               const float* __restrict__ W0,
                                               const float* __restrict__ R,
                                               unsigned short* __restrict__ w2,
                                               unsigned short* __restrict__ w0f,
                                               unsigned short* __restrict__ biasT) {
    if (blockIdx.x < 8192) {
        int gidx = blockIdx.x * 256 + threadIdx.x;       // [0, 2097152)
        int lane = gidx & 63, slot = gidx >> 6;          // slot in [0, 32768)
        int tjk = slot & 63, tq = (slot >> 6) & 63, h = slot >> 12;
        int q = lane >> 4, n = lane & 15;
        int i = 16 * tq + n;                              // query
        int ix = i >> 5, iy = i & 31;
        const float* Rh = R + (h << 10);
        unsigned short v[4];
        for (int r = 0; r < 4; ++r) {
            int j = 16 * tjk + 4 * q + r;                 // key
            int jx = j >> 5, jy = j & 31;
            float val = Rh[(((ix - jx) & 31) << 5) + ((iy - jy) & 31)] * SCL;
            v[r] = f2bf(val);
        }
        unsigned long long pk = (unsigned long long)v[0] | ((unsigned long long)v[1] << 16) |
                                ((unsigned long long)v[2] << 32) | ((unsigned long long)v[3] << 48);
        *(unsigned long long*)&biasT[(size_t)gidx * 4] = pk;
    } else {
        int idx = (blockIdx.x - 8192) * 256 + threadIdx.x;  // [0, 262144)
        if (idx < 196608) {
            int row = idx >> 7, col = idx & 127;
            float v;
            if (row < 512)       v = Wq[idx] * SCL;
            else if (row < 1024) v = Wk[idx - 65536];
            else                 v = Wv[idx - 131072];
            int rt = row >> 4, nr = row & 15, kc = col >> 5, qc = (col & 31) >> 3, jc = col & 7;
            w2[((rt * 4 + kc) * 512) + (qc * 16 + nr) * 8 + jc] = f2bf(v);
        } else {
            int idx2 = idx - 196608;
            int row = idx2 >> 9, col = idx2 & 511;
            int rt = row >> 4, nr = row & 15, kcA = col >> 5, qc = (col & 31) >> 3, jc = col & 7;
            w0f[((rt * 16 + kcA) * 512) + (qc * 16 + nr) * 8 + jc] = f2bf(W0[idx2]);
        }
    }
}

// xt2: x transposed+scaled, in B/A fragment order over (b, pt=pos/16, kc=c/32).
__global__ __launch_bounds__(256) void prep_xt(const float* __restrict__ x,
                                               unsigned short* __restrict__ xt2) {
    __shared__ float lds[64 * 65];
    int b = blockIdx.x, c0 = blockIdx.y * 64, p0 = blockIdx.z * 64;
    int t = threadIdx.x, tr = t >> 6, tc = t & 63;
    const float inv_layer = 0.44721359549995793f;  // 1/sqrt(5)
    for (int rr = 0; rr < 16; ++rr) {
        int cl = rr * 4 + tr;
        lds[cl * 65 + tc] = x[(b * CIN + c0 + cl) * SEQ + p0 + tc];
    }
    __syncthreads();
    for (int rr = 0; rr < 16; ++rr) {
        int pl = rr * 4 + tr;
        int pos = p0 + pl, c = c0 + tc;
        int pt = pos >> 4, np = pos & 15, kc = c >> 5, qc = (c & 31) >> 3, jc = c & 7;
        xt2[((size_t)((b * 64 + pt) * 4 + kc) * 512) + (qc * 16 + np) * 8 + jc] =
            f2bf(lds[tc * 65 + pl] * inv_layer);
    }
}

// ---------------- fused QKV projection ----------------
// y in [0,16): Q/K, A = wqkv rows (m=wrow), B = xt (n=pos). D row = wrow.
//   Q (y<8)  -> natural (b,h,pos,d), 8B packed stores.
//   K (y>=8) -> Kf A-frag order (m=key): d in regs -> 8B stores.
// y in [16,24): V, A = xt (m=pos), B = Wv rows (n=vrow). D row = pos=key.
//   -> Vf A-frag order with PV k-permutation folded in, 8B stores.
__global__ __launch_bounds__(256, 4) void qkv_gemm(const unsigned short* __restrict__ xt2,
                                                   const unsigned short* __restrict__ w2,
                                                   unsigned short* __restrict__ Qt,
                                                   unsigned short* __restrict__ Kf,
                                                   unsigned short* __restrict__ Vf) {
    int b = blockIdx.x, y = blockIdx.y, zt = blockIdx.z;
    int tid = threadIdx.x, wave = tid >> 6, lane = tid & 63, q = lane >> 4, n = lane & 15;
    floatx4 acc[4];
    for (int s = 0; s < 4; ++s) acc[s] = (floatx4){0.f, 0.f, 0.f, 0.f};
    bf16x8 af[4], bfr[4][4];
    if (y < 16) {
        int rt = y * 4 + wave;                       // wrow tile
        const unsigned short* wbase = w2 + (size_t)rt * 4 * 512 + lane * 8;
        const unsigned short* xbase = xt2 + (size_t)(b * 64 + zt * 4) * 4 * 512 + lane * 8;
        for (int kc = 0; kc < 4; ++kc) af[kc] = ldfrag(wbase + kc * 512);
        for (int s = 0; s < 4; ++s)
            for (int kc = 0; kc < 4; ++kc) bfr[s][kc] = ldfrag(xbase + (s * 4 + kc) * 512);
        for (int kc = 0; kc < 4; ++kc)
            for (int s = 0; s < 4; ++s)
                acc[s] = __builtin_amdgcn_mfma_f32_16x16x32_bf16(af[kc], bfr[s][kc], acc[s], 0, 0, 0);
        int wrow0 = y * 64 + wave * 16;
        int pos0 = zt * 64;
        if (y < 8) {
            int h = wrow0 >> 6;
            int d0 = (wrow0 & 63) + 4 * q;
            for (int s = 0; s < 4; ++s) {
                uint2 pk;
                pk.x = pkbf(acc[s][0], acc[s][1]);
                pk.y = pkbf(acc[s][2], acc[s][3]);
                int pos = pos0 + 16 * s + n;
                *(uint2*)&Qt[((size_t)(b * NH + h) * SEQ + pos) * DKH + d0] = pk;
            }
        } else {
            // K: d = wave*16+4q+r (regs), key = 16s+n. A-frag store:
            // frag (s, c=wave>>1), lane (qk = 2(wave&1)+(q>>1), n), jk = 4(q&1)+r
            int h = (wrow0 >> 6) - 8;
            int bh = b * NH + h;
            int cd = wave >> 1;
            int qk = 2 * (wave & 1) + (q >> 1);
            int jk = 4 * (q & 1);
            for (int s = 0; s < 4; ++s) {
                uint2 pk;
                pk.x = pkbf(acc[s][0], acc[s][1]);
                pk.y = pkbf(acc[s][2], acc[s][3]);
                size_t addr = ((size_t)(bh * 16 + zt) * 8 + s * 2 + cd) * 512
                              + (qk * 16 + n) * 8 + jk;
                *(uint2*)&Kf[addr] = pk;
            }
        }
    } else {
        int pt = zt * 4 + wave;                      // pos tile
        const unsigned short* xbase = xt2 + (size_t)((b * 64 + pt) * 4) * 512 + lane * 8;
        int rtv0 = 64 + (y - 16) * 4;                // V wrow tiles start at row 1024
        const unsigned short* wbase = w2 + (size_t)rtv0 * 4 * 512 + lane * 8;
        for (int kc = 0; kc < 4; ++kc) af[kc] = ldfrag(xbase + kc * 512);
        for (int s = 0; s < 4; ++s)
            for (int kc = 0; kc < 4; ++kc) bfr[s][kc] = ldfrag(wbase + (s * 4 + kc) * 512);
        for (int kc = 0; kc < 4; ++kc)
            for (int s = 0; s < 4; ++s)
                acc[s] = __builtin_amdgcn_mfma_f32_16x16x32_bf16(af[kc], bfr[s][kc], acc[s], 0, 0, 0);
        // V: key = wave*16+4q+r (regs), vrow = vrow0+16s+n -> (h, d).
        // Vf A-frag (u=d>>4, c=wave>>1), lane (q, d&15), jj = 4(wave&1)+r
        int vrow0 = (y - 16) * 64;
        int cj = wave >> 1;
        int jj0 = 4 * (wave & 1);
        for (int s = 0; s < 4; ++s) {
            int vrow = vrow0 + 16 * s + n;
            int h = vrow >> 6, d = vrow & 63;
            int u = d >> 4, nl = d & 15;
            uint2 pk;
            pk.x = pkbf(acc[s][0], acc[s][1]);
            pk.y = pkbf(acc[s][2], acc[s][3]);
            size_t addr = ((size_t)((b * NH + h) * 16 + zt) * 8 + u * 2 + cj) * 512
                          + (q * 16 + nl) * 8 + jj0;
            *(uint2*)&Vf[addr] = pk;
        }
    }
}

// ---------------- attention (transposed, register-resident P) ----------------
// WG = 256 queries (4 waves x 64, as 4 n-tiles of 16); key tiles of 64.
// gid&255 = (b,h) -> one head per XCD. K/V staged via LDS (16KB) with
// register prefetch of tile kt+1. S^T = K Q^T; P^T packed in-lane to
// B-frags; O^T = V^T P^T; l via ones-MFMA.
__global__ __launch_bounds__(256, 2) void attn_kernel(const unsigned short* __restrict__ Qt,
                                                      const unsigned short* __restrict__ Kf,
                                                      const unsigned short* __restrict__ Vf,
                                                      const unsigned short* __restrict__ biasT,
                                                      unsigned short* __restrict__ att2) {
    __shared__ alignas(16) unsigned short lds_k[8 * 512];    // A-frag K tile
    __shared__ alignas(16) unsigned short lds_v[8 * 512];    // A-frag V tile

    int gid = blockIdx.x;
    int bh = gid & 255, qb = gid >> 8;
    int b = bh >> 3, h = bh & 7;
    int tid = threadIdx.x, wave = tid >> 6, lane = tid & 63, q = lane >> 4, n = lane & 15;
    int i0 = qb * 256 + wave * 64;
    int ti0 = i0 >> 4;

    const unsigned short* qbase = Qt + (size_t)bh * SEQ * DKH;
    const unsigned short* kft = Kf + (size_t)bh * 16 * 4096;
    const unsigned short* vft = Vf + (size_t)bh * 16 * 4096;
    const unsigned short* bT = biasT + (size_t)h * 64 * 64 * 256;

    // Q as B-fragments: lane (q,n): query = i0+16qt+n, d = c*32+8q+j
    bf16x8 aq[4][2];
    for (int qt = 0; qt < 4; ++qt)
        for (int c = 0; c < 2; ++c)
            aq[qt][c] = ldfrag(qbase + (i0 + 16 * qt + n) * DKH + c * 32 + q * 8);

    // all-ones A fragment for column-sum MFMA (l = 1^T P^T)
    u16x8 ones_u;
    for (int t = 0; t < 8; ++t) ones_u[t] = 0x3F80;
    bf16x8 vone = __builtin_bit_cast(bf16x8, ones_u);

    floatx4 o[4][4], acc_l[4];
    for (int qt = 0; qt < 4; ++qt) {
        acc_l[qt] = (floatx4){0.f, 0.f, 0.f, 0.f};
        for (int u = 0; u < 4; ++u) o[qt][u] = (floatx4){0.f, 0.f, 0.f, 0.f};
    }

    // register prefetch of tile 0
    u16x8 kpre0, kpre1, vpre0, vpre1;
    {
        const unsigned short* kp = kft + tid * 16;
        const unsigned short* vp = vft + tid * 16;
        kpre0 = *(const u16x8*)kp;  kpre1 = *(const u16x8*)(kp + 8);
        vpre0 = *(const u16x8*)vp;  vpre1 = *(const u16x8*)(vp + 8);
    }

    for (int kt = 0; kt < 16; ++kt) {
        __syncthreads();  // prior iter's LDS reads done
        *(u16x8*)&lds_k[tid * 16]     = kpre0;
        *(u16x8*)&lds_k[tid * 16 + 8] = kpre1;
        *(u16x8*)&lds_v[tid * 16]     = vpre0;
        *(u16x8*)&lds_v[tid * 16 + 8] = vpre1;
        __syncthreads();
        if (kt < 15) {  // prefetch next tile; latency hidden behind compute
            const unsigned short* kp = kft + (kt + 1) * 4096 + tid * 16;
            const unsigned short* vp = vft + (kt + 1) * 4096 + tid * 16;
            kpre0 = *(const u16x8*)kp;  kpre1 = *(const u16x8*)(kp + 8);
            vpre0 = *(const u16x8*)vp;  vpre1 = *(const u16x8*)(vp + 8);
        }

        // bias loads for this key tile (16 x uint2, L2-resident)
        uint2 bl[4][4];
        for (int qt = 0; qt < 4; ++qt)
            for (int s = 0; s < 4; ++s)
                bl[qt][s] = *(const uint2*)(bT + (((size_t)(ti0 + qt) * 64 + kt * 4 + s) << 8) + lane * 4);

        // K fragments (shared across the 4 query tiles)
        bf16x8 kf2[4][2];
        for (int s = 0; s < 4; ++s)
            for (int c = 0; c < 2; ++c)
                kf2[s][c] = ldfrag(&lds_k[(s * 2 + c) * 512 + lane * 8]);

        // S^T = K Q^T + bias^T; P^T = exp2 -> packed B-frags (registers only)
        bf16x8 pf[4][2];
        for (int qt = 0; qt < 4; ++qt) {
            floatx4 sv[4];
            for (int s = 0; s < 4; ++s) {
                sv[s] = (floatx4){bfhi(bl[qt][s].x), bflo(bl[qt][s].x),
                                  bfhi(bl[qt][s].y), bflo(bl[qt][s].y)};
                sv[s] = __builtin_amdgcn_mfma_f32_16x16x32_bf16(kf2[s][0], aq[qt][0], sv[s], 0, 0, 0);
                sv[s] = __builtin_amdgcn_mfma_f32_16x16x32_bf16(kf2[s][1], aq[qt][1], sv[s], 0, 0, 0);
            }
            for (int c = 0; c < 2; ++c) {
                uintx4 pu;
                pu[0] = pkbf(__builtin_amdgcn_exp2f(sv[2 * c][0]), __builtin_amdgcn_exp2f(sv[2 * c][1]));
                pu[1] = pkbf(__builtin_amdgcn_exp2f(sv[2 * c][2]), __builtin_amdgcn_exp2f(sv[2 * c][3]));
                pu[2] = pkbf(__builtin_amdgcn_exp2f(sv[2 * c + 1][0]), __builtin_amdgcn_exp2f(sv[2 * c + 1][1]));
                pu[3] = pkbf(__builtin_amdgcn_exp2f(sv[2 * c + 1][2]), __builtin_amdgcn_exp2f(sv[2 * c + 1][3]));
                pf[qt][c] = __builtin_bit_cast(bf16x8, pu);
            }
        }

        // V fragments, then O^T += V^T P^T ; l += 1^T P^T
        bf16x8 vf2[4][2];
        for (int u = 0; u < 4; ++u)
            for (int c = 0; c < 2; ++c)
                vf2[u][c] = ldfrag(&lds_v[(u * 2 + c) * 512 + lane * 8]);
        for (int qt = 0; qt < 4; ++qt) {
            acc_l[qt] = __builtin_amdgcn_mfma_f32_16x16x32_bf16(vone, pf[qt][0], acc_l[qt], 0, 0, 0);
            acc_l[qt] = __builtin_amdgcn_mfma_f32_16x16x32_bf16(vone, pf[qt][1], acc_l[qt], 0, 0, 0);
        }
        for (int u = 0; u < 4; ++u)
            for (int qt = 0; qt < 4; ++qt) {
                o[qt][u] = __builtin_amdgcn_mfma_f32_16x16x32_bf16(vf2[u][0], pf[qt][0], o[qt][u], 0, 0, 0);
                o[qt][u] = __builtin_amdgcn_mfma_f32_16x16x32_bf16(vf2[u][1], pf[qt][1], o[qt][u], 0, 0, 0);
            }
    }

    // epilogue: O^T lane (q,n): query = i0+16qt+n, d = 16u+4q+r.
    // att2 A-frag order: (pos=query, hd=h*64+d): kcA = 2h+(u>>1),
    // q2 = 2(u&1)+(q>>1), j2 = 4(q&1)+r, n2 = n.  l broadcast per lane.
    for (int qt = 0; qt < 4; ++qt) {
        float inv = 1.0f / acc_l[qt][0];
        int pt = ti0 + qt;
        for (int u = 0; u < 4; ++u) {
            int kcA = 2 * h + (u >> 1);
            int q2 = 2 * (u & 1) + (q >> 1);
            uint2 pk;
            pk.x = pkbf(o[qt][u][0] * inv, o[qt][u][1] * inv);
            pk.y = pkbf(o[qt][u][2] * inv, o[qt][u][3] * inv);
            size_t addr = ((size_t)((b * 64 + pt) * 16 + kcA) * 512)
                          + (q2 * 16 + n) * 8 + 4 * (q & 1);
            *(uint2*)&att2[addr] = pk;
        }
    }
}

// ---------------- output projection + residual ----------------
// A = att2 (m=pos), B = w0f (n=c); K=512 in 4 hoisted groups of 4 kcA.
__global__ __launch_bounds__(256, 4) void out_gemm(const unsigned short* __restrict__ att2,
                                                   const unsigned short* __restrict__ w0f,
                                                   const float* __restrict__ x,
                                                   float* __restrict__ out) {
    int b = blockIdx.x, ct = blockIdx.y, ptb = blockIdx.z;
    int tid = threadIdx.x, wave = tid >> 6, lane = tid & 63, q = lane >> 4, n = lane & 15;
    int pos0 = ptb * 64 + wave * 16;
    int c0 = ct * 64;
    int pt = ptb * 4 + wave;
    const unsigned short* abase = att2 + (size_t)(b * 64 + pt) * 16 * 512 + lane * 8;
    const unsigned short* wbase = w0f + (size_t)(c0 >> 4) * 16 * 512 + lane * 8;
    floatx4 acc[4];
    for (int s = 0; s < 4; ++s) acc[s] = (floatx4){0.f, 0.f, 0.f, 0.f};
    for (int g = 0; g < 4; ++g) {
        bf16x8 af[4], bfr[4][4];
        for (int k2 = 0; k2 < 4; ++k2) af[k2] = ldfrag(abase + (g * 4 + k2) * 512);
        for (int s = 0; s < 4; ++s)
            for (int k2 = 0; k2 < 4; ++k2)
                bfr[s][k2] = ldfrag(wbase + (s * 16 + g * 4 + k2) * 512);
        for (int k2 = 0; k2 < 4; ++k2)
            for (int s = 0; s < 4; ++s)
                acc[s] = __builtin_amdgcn_mfma_f32_16x16x32_bf16(af[k2], bfr[s][k2], acc[s], 0, 0, 0);
    }
    int p0q = pos0 + 4 * q;
    for (int s = 0; s < 4; ++s) {
        int c = c0 + 16 * s + n;
        size_t idx = ((size_t)b * CIN + c) * SEQ + p0q;
        floatx4 res = *(const floatx4*)&x[idx];
        floatx4 v = acc[s] + res;
        *(floatx4*)&out[idx] = v;
    }
}

// ---------------- launch ----------------
extern "C" void kernel_launch(void* const* d_in, const int* in_sizes, int n_in,
                              void* d_out, int out_size, void* d_ws, size_t ws_size,
                              hipStream_t stream) {
    const float* x  = (const float*)d_in[0];
    const float* Wq = (const float*)d_in[1];
    const float* Wk = (const float*)d_in[2];
    const float* Wv = (const float*)d_in[3];
    const float* R  = (const float*)d_in[4];
    const float* W0 = (const float*)d_in[5];
    float* out = (float*)d_out;

    char* ws = (char*)d_ws;
    size_t off = 0;
    unsigned short* Qt   = (unsigned short*)(ws + off); off += (size_t)NB * NH * SEQ * DKH * 2;
    unsigned short* Kf   = (unsigned short*)(ws + off); off += (size_t)NB * NH * SEQ * DKH * 2;
    unsigned short* Vf   = (unsigned short*)(ws + off); off += (size_t)NB * NH * SEQ * DKH * 2;
    unsigned short* att2 = (unsigned short*)(ws + off); off += (size_t)NB * SEQ * HDIM * 2;
    unsigned short* xt2  = (unsigned short*)(ws + off); off += (size_t)NB * SEQ * CIN * 2;
    unsigned short* w2   = (unsigned short*)(ws + off); off += (size_t)1536 * 128 * 2;
    unsigned short* w0f  = (unsigned short*)(ws + off); off += (size_t)128 * 512 * 2;
    unsigned short* biasT= (unsigned short*)(ws + off); off += (size_t)NH * (SEQ/16) * (SEQ/16) * 256 * 2;
    (void)ws_size; (void)in_sizes; (void)n_in; (void)out_size;

    prep_wb<<<9216, 256, 0, stream>>>(Wq, Wk, Wv, W0, R, w2, w0f, biasT);
    prep_xt<<<dim3(NB, 2, 16), 256, 0, stream>>>(x, xt2);
    qkv_gemm<<<dim3(NB, 24, 16), 256, 0, stream>>>(xt2, w2, Qt, Kf, Vf);
    attn_kernel<<<NB * NH * 4, 256, 0, stream>>>(Qt, Kf, Vf, biasT, att2);
    out_gemm<<<dim3(NB, 2, 16), 256, 0, stream>>>(att2, w0f, x, out);
}

// Round 9
// 229.355 us; speedup vs baseline: 1.4767x; 1.0518x over previous
//
#include <hip/hip_runtime.h>

// CvT block, MI355X bf16-MFMA implementation.
// B=32, C=128, L=32 (seq=1024), H=8, DK=64, HD=512, NLAYER=4.
// R9: attn is instruction-issue bound (R5 3-wave and R8 2-wave both ~70
// SIMD-cyc/query; no pipe >45%). Cut VALU volume: (a) bias pre-stored f32
// in C-fragment layout, loaded dwordx4 straight into the MFMA C operand
// (kills ~128 unpack insts/wave-iter); (b) truncation-pack P via bare
// v_perm (P>0, l self-consistent; kills RNE adds). Structure = R8.

#define NB   32
#define NH   8
#define SEQ  1024
#define DKH  64
#define HDIM 512
#define CIN  128

// 0.125 * log2(e): folded into Wq and bias so scores are in exp2 domain.
#define SCL 0.18033688011112042f

typedef __bf16 bf16x8 __attribute__((ext_vector_type(8)));
typedef float floatx4 __attribute__((ext_vector_type(4)));
typedef unsigned short u16x8 __attribute__((ext_vector_type(8)));
typedef unsigned int uintx4 __attribute__((ext_vector_type(4)));

__device__ __forceinline__ unsigned short f2bf(float f) {
    union { float f; unsigned int u; } c; c.f = f;
    unsigned int u = c.u;
    return (unsigned short)((u + 0x7fffu + ((u >> 16) & 1u)) >> 16); // RNE
}
__device__ __forceinline__ bf16x8 ldfrag(const unsigned short* p) {
    u16x8 v = *reinterpret_cast<const u16x8*>(p);
    return __builtin_bit_cast(bf16x8, v);
}
// pack two f32 -> two RNE bf16; 'a' lands in the LOW short.
__device__ __forceinline__ unsigned int pkbf(float a, float b) {
    unsigned int ua = __builtin_bit_cast(unsigned int, a);
    unsigned int ub = __builtin_bit_cast(unsigned int, b);
    ua += 0x7fffu + ((ua >> 16) & 1u);
    ub += 0x7fffu + ((ub >> 16) & 1u);
    return __builtin_amdgcn_perm(ub, ua, 0x07060302u);
}
// truncation pack (P>0): one v_perm, no rounding adds.
__device__ __forceinline__ unsigned int pkbf_t(float a, float b) {
    return __builtin_amdgcn_perm(__builtin_bit_cast(unsigned int, b),
                                 __builtin_bit_cast(unsigned int, a), 0x07060302u);
}

// Fragment-order storage: 512-elem block = one wave fragment [lane][j].
// Kf (A-frag, m=key): frag (s,c): lane (q,n) j <-> K[key=16s+n][d=32c+8q+j]
// Vf (A-frag, m=d, permuted k): frag (u,c): lane (q,n) jj <->
//     V[key = 32c+16(jj>>2)+4q+(jj&3)][d=16u+n]   (matches P^T pack order)

// ---------------- prep: weights + transposed f32 bias ----------------
// blocks [0, 8192): biasF f32 C-frag order for S^T: slot = (h*64+tq)*64+tjk,
//   biasF[slot*256 + lane*4 + r] = bias[query=16tq+n][key=16tjk+4q+r]*SCL.
// blocks [8192, 9216): weight casts; Wq scaled by SCL (exp2 domain).
__global__ __launch_bounds__(256) void prep_wb(const float* __restrict__ Wq,
                                               const float* __restrict__ Wk,
                                               const float* __restrict__ Wv,
                                               const float* __restrict__ W0,
                                               const float* __restrict__ R,
                                               unsigned short* __restrict__ w2,
                                               unsigned short* __restrict__ w0f,
                                               float* __restrict__ biasF) {
    if (blockIdx.x < 8192) {
        int gidx = blockIdx.x * 256 + threadIdx.x;       // [0, 2097152)
        int lane = gidx & 63, slot = gidx >> 6;          // slot in [0, 32768)
        int tjk = slot & 63, tq = (slot >> 6) & 63, h = slot >> 12;
        int q = lane >> 4, n = lane & 15;
        int i = 16 * tq + n;                              // query
        int ix = i >> 5, iy = i & 31;
        const float* Rh = R + (h << 10);
        floatx4 v;
        for (int r = 0; r < 4; ++r) {
            int j = 16 * tjk + 4 * q + r;                 // key
            int jx = j >> 5, jy = j & 31;
            v[r] = Rh[(((ix - jx) & 31) << 5) + ((iy - jy) & 31)] * SCL;
        }
        *(floatx4*)&biasF[(size_t)gidx * 4] = v;
    } else {
        int idx = (blockIdx.x - 8192) * 256 + threadIdx.x;  // [0, 262144)
        if (idx < 196608) {
            int row = idx >> 7, col = idx & 127;
            float v;
            if (row < 512)       v = Wq[idx] * SCL;
            else if (row < 1024) v = Wk[idx - 65536];
            else                 v = Wv[idx - 131072];
            int rt = row >> 4, nr = row & 15, kc = col >> 5, qc = (col & 31) >> 3, jc = col & 7;
            w2[((rt * 4 + kc) * 512) + (qc * 16 + nr) * 8 + jc] = f2bf(v);
        } else {
            int idx2 = idx - 196608;
            int row = idx2 >> 9, col = idx2 & 511;
            int rt = row >> 4, nr = row & 15, kcA = col >> 5, qc = (col & 31) >> 3, jc = col & 7;
            w0f[((rt * 16 + kcA) * 512) + (qc * 16 + nr) * 8 + jc] = f2bf(W0[idx2]);
        }
    }
}

// xt2: x transposed+scaled, in B/A fragment order over (b, pt=pos/16, kc=c/32).
__global__ __launch_bounds__(256) void prep_xt(const float* __restrict__ x,
                                               unsigned short* __restrict__ xt2) {
    __shared__ float lds[64 * 65];
    int b = blockIdx.x, c0 = blockIdx.y * 64, p0 = blockIdx.z * 64;
    int t = threadIdx.x, tr = t >> 6, tc = t & 63;
    const float inv_layer = 0.44721359549995793f;  // 1/sqrt(5)
    for (int rr = 0; rr < 16; ++rr) {
        int cl = rr * 4 + tr;
        lds[cl * 65 + tc] = x[(b * CIN + c0 + cl) * SEQ + p0 + tc];
    }
    __syncthreads();
    for (int rr = 0; rr < 16; ++rr) {
        int pl = rr * 4 + tr;
        int pos = p0 + pl, c = c0 + tc;
        int pt = pos >> 4, np = pos & 15, kc = c >> 5, qc = (c & 31) >> 3, jc = c & 7;
        xt2[((size_t)((b * 64 + pt) * 4 + kc) * 512) + (qc * 16 + np) * 8 + jc] =
            f2bf(lds[tc * 65 + pl] * inv_layer);
    }
}

// ---------------- fused QKV projection ----------------
__global__ __launch_bounds__(256, 4) void qkv_gemm(const unsigned short* __restrict__ xt2,
                                                   const unsigned short* __restrict__ w2,
                                                   unsigned short* __restrict__ Qt,
                                                   unsigned short* __restrict__ Kf,
                                                   unsigned short* __restrict__ Vf) {
    int b = blockIdx.x, y = blockIdx.y, zt = blockIdx.z;
    int tid = threadIdx.x, wave = tid >> 6, lane = tid & 63, q = lane >> 4, n = lane & 15;
    floatx4 acc[4];
    for (int s = 0; s < 4; ++s) acc[s] = (floatx4){0.f, 0.f, 0.f, 0.f};
    bf16x8 af[4], bfr[4][4];
    if (y < 16) {
        int rt = y * 4 + wave;                       // wrow tile
        const unsigned short* wbase = w2 + (size_t)rt * 4 * 512 + lane * 8;
        const unsigned short* xbase = xt2 + (size_t)(b * 64 + zt * 4) * 4 * 512 + lane * 8;
        for (int kc = 0; kc < 4; ++kc) af[kc] = ldfrag(wbase + kc * 512);
        for (int s = 0; s < 4; ++s)
            for (int kc = 0; kc < 4; ++kc) bfr[s][kc] = ldfrag(xbase + (s * 4 + kc) * 512);
        for (int kc = 0; kc < 4; ++kc)
            for (int s = 0; s < 4; ++s)
                acc[s] = __builtin_amdgcn_mfma_f32_16x16x32_bf16(af[kc], bfr[s][kc], acc[s], 0, 0, 0);
        int wrow0 = y * 64 + wave * 16;
        int pos0 = zt * 64;
        if (y < 8) {
            int h = wrow0 >> 6;
            int d0 = (wrow0 & 63) + 4 * q;
            for (int s = 0; s < 4; ++s) {
                uint2 pk;
                pk.x = pkbf(acc[s][0], acc[s][1]);
                pk.y = pkbf(acc[s][2], acc[s][3]);
                int pos = pos0 + 16 * s + n;
                *(uint2*)&Qt[((size_t)(b * NH + h) * SEQ + pos) * DKH + d0] = pk;
            }
        } else {
            // K: d = wave*16+4q+r (regs), key = 16s+n. A-frag store.
            int h = (wrow0 >> 6) - 8;
            int bh = b * NH + h;
            int cd = wave >> 1;
            int qk = 2 * (wave & 1) + (q >> 1);
            int jk = 4 * (q & 1);
            for (int s = 0; s < 4; ++s) {
                uint2 pk;
                pk.x = pkbf(acc[s][0], acc[s][1]);
                pk.y = pkbf(acc[s][2], acc[s][3]);
                size_t addr = ((size_t)(bh * 16 + zt) * 8 + s * 2 + cd) * 512
                              + (qk * 16 + n) * 8 + jk;
                *(uint2*)&Kf[addr] = pk;
            }
        }
    } else {
        int pt = zt * 4 + wave;                      // pos tile
        const unsigned short* xbase = xt2 + (size_t)((b * 64 + pt) * 4) * 512 + lane * 8;
        int rtv0 = 64 + (y - 16) * 4;                // V wrow tiles start at row 1024
        const unsigned short* wbase = w2 + (size_t)rtv0 * 4 * 512 + lane * 8;
        for (int kc = 0; kc < 4; ++kc) af[kc] = ldfrag(xbase + kc * 512);
        for (int s = 0; s < 4; ++s)
            for (int kc = 0; kc < 4; ++kc) bfr[s][kc] = ldfrag(wbase + (s * 4 + kc) * 512);
        for (int kc = 0; kc < 4; ++kc)
            for (int s = 0; s < 4; ++s)
                acc[s] = __builtin_amdgcn_mfma_f32_16x16x32_bf16(af[kc], bfr[s][kc], acc[s], 0, 0, 0);
        // V: key = wave*16+4q+r (regs) -> Vf A-frag with PV k-permutation.
        int vrow0 = (y - 16) * 64;
        int cj = wave >> 1;
        int jj0 = 4 * (wave & 1);
        for (int s = 0; s < 4; ++s) {
            int vrow = vrow0 + 16 * s + n;
            int h = vrow >> 6, d = vrow & 63;
            int u = d >> 4, nl = d & 15;
            uint2 pk;
            pk.x = pkbf(acc[s][0], acc[s][1]);
            pk.y = pkbf(acc[s][2], acc[s][3]);
            size_t addr = ((size_t)((b * NH + h) * 16 + zt) * 8 + u * 2 + cj) * 512
                          + (q * 16 + nl) * 8 + jj0;
            *(uint2*)&Vf[addr] = pk;
        }
    }
}

// ---------------- attention (transposed, register-resident P) ----------------
// WG = 256 queries (4 waves x 64, as 4 n-tiles of 16); key tiles of 64.
// gid&255 = (b,h) -> one head per XCD. S^T = K Q^T with f32 bias as the
// MFMA C operand; P^T trunc-packed in-lane to B-frags; O^T = V^T P^T.
__global__ __launch_bounds__(256, 2) void attn_kernel(const unsigned short* __restrict__ Qt,
                                                      const unsigned short* __restrict__ Kf,
                                                      const unsigned short* __restrict__ Vf,
                                                      const float* __restrict__ biasF,
                                                      unsigned short* __restrict__ att2) {
    __shared__ alignas(16) unsigned short lds_k[8 * 512];    // A-frag K tile
    __shared__ alignas(16) unsigned short lds_v[8 * 512];    // A-frag V tile

    int gid = blockIdx.x;
    int bh = gid & 255, qb = gid >> 8;
    int b = bh >> 3, h = bh & 7;
    int tid = threadIdx.x, wave = tid >> 6, lane = tid & 63, q = lane >> 4, n = lane & 15;
    int i0 = qb * 256 + wave * 64;
    int ti0 = i0 >> 4;

    const unsigned short* qbase = Qt + (size_t)bh * SEQ * DKH;
    const unsigned short* kft = Kf + (size_t)bh * 16 * 4096;
    const unsigned short* vft = Vf + (size_t)bh * 16 * 4096;
    const float* bF = biasF + ((size_t)h * 64 * 64 * 256) + lane * 4;

    // Q as B-fragments: lane (q,n): query = i0+16qt+n, d = c*32+8q+j
    bf16x8 aq[4][2];
    for (int qt = 0; qt < 4; ++qt)
        for (int c = 0; c < 2; ++c)
            aq[qt][c] = ldfrag(qbase + (i0 + 16 * qt + n) * DKH + c * 32 + q * 8);

    // all-ones A fragment for column-sum MFMA (l = 1^T P^T)
    u16x8 ones_u;
    for (int t = 0; t < 8; ++t) ones_u[t] = 0x3F80;
    bf16x8 vone = __builtin_bit_cast(bf16x8, ones_u);

    floatx4 o[4][4], acc_l[4];
    for (int qt = 0; qt < 4; ++qt) {
        acc_l[qt] = (floatx4){0.f, 0.f, 0.f, 0.f};
        for (int u = 0; u < 4; ++u) o[qt][u] = (floatx4){0.f, 0.f, 0.f, 0.f};
    }

    // register prefetch of tile 0
    u16x8 kpre0, kpre1, vpre0, vpre1;
    {
        const unsigned short* kp = kft + tid * 16;
        const unsigned short* vp = vft + tid * 16;
        kpre0 = *(const u16x8*)kp;  kpre1 = *(const u16x8*)(kp + 8);
        vpre0 = *(const u16x8*)vp;  vpre1 = *(const u16x8*)(vp + 8);
    }

    for (int kt = 0; kt < 16; ++kt) {
        __syncthreads();  // prior iter's LDS reads done
        *(u16x8*)&lds_k[tid * 16]     = kpre0;
        *(u16x8*)&lds_k[tid * 16 + 8] = kpre1;
        *(u16x8*)&lds_v[tid * 16]     = vpre0;
        *(u16x8*)&lds_v[tid * 16 + 8] = vpre1;
        __syncthreads();
        if (kt < 15) {  // prefetch next tile; latency hidden behind compute
            const unsigned short* kp = kft + (kt + 1) * 4096 + tid * 16;
            const unsigned short* vp = vft + (kt + 1) * 4096 + tid * 16;
            kpre0 = *(const u16x8*)kp;  kpre1 = *(const u16x8*)(kp + 8);
            vpre0 = *(const u16x8*)vp;  vpre1 = *(const u16x8*)(vp + 8);
        }

        // f32 bias C-fragments for this key tile (16 dwordx4, L2-resident)
        floatx4 bsv[4][4];
        for (int qt = 0; qt < 4; ++qt)
            for (int s = 0; s < 4; ++s)
                bsv[qt][s] = *(const floatx4*)(bF + (((size_t)(ti0 + qt) * 64 + kt * 4 + s) << 8));

        // K fragments (shared across the 4 query tiles)
        bf16x8 kf2[4][2];
        for (int s = 0; s < 4; ++s)
            for (int c = 0; c < 2; ++c)
                kf2[s][c] = ldfrag(&lds_k[(s * 2 + c) * 512 + lane * 8]);

        // S^T = K Q^T + bias^T (C-init); P^T = exp2 -> packed B-frags
        bf16x8 pf[4][2];
        for (int qt = 0; qt < 4; ++qt) {
            floatx4 sv[4];
            for (int s = 0; s < 4; ++s) {
                sv[s] = __builtin_amdgcn_mfma_f32_16x16x32_bf16(kf2[s][0], aq[qt][0], bsv[qt][s], 0, 0, 0);
                sv[s] = __builtin_amdgcn_mfma_f32_16x16x32_bf16(kf2[s][1], aq[qt][1], sv[s], 0, 0, 0);
            }
            for (int c = 0; c < 2; ++c) {
                uintx4 pu;
                pu[0] = pkbf_t(__builtin_amdgcn_exp2f(sv[2 * c][0]), __builtin_amdgcn_exp2f(sv[2 * c][1]));
                pu[1] = pkbf_t(__builtin_amdgcn_exp2f(sv[2 * c][2]), __builtin_amdgcn_exp2f(sv[2 * c][3]));
                pu[2] = pkbf_t(__builtin_amdgcn_exp2f(sv[2 * c + 1][0]), __builtin_amdgcn_exp2f(sv[2 * c + 1][1]));
                pu[3] = pkbf_t(__builtin_amdgcn_exp2f(sv[2 * c + 1][2]), __builtin_amdgcn_exp2f(sv[2 * c + 1][3]));
                pf[qt][c] = __builtin_bit_cast(bf16x8, pu);
            }
        }

        // V fragments, then O^T += V^T P^T ; l += 1^T P^T
        bf16x8 vf2[4][2];
        for (int u = 0; u < 4; ++u)
            for (int c = 0; c < 2; ++c)
                vf2[u][c] = ldfrag(&lds_v[(u * 2 + c) * 512 + lane * 8]);
        for (int qt = 0; qt < 4; ++qt) {
            acc_l[qt] = __builtin_amdgcn_mfma_f32_16x16x32_bf16(vone, pf[qt][0], acc_l[qt], 0, 0, 0);
            acc_l[qt] = __builtin_amdgcn_mfma_f32_16x16x32_bf16(vone, pf[qt][1], acc_l[qt], 0, 0, 0);
        }
        for (int u = 0; u < 4; ++u)
            for (int qt = 0; qt < 4; ++qt) {
                o[qt][u] = __builtin_amdgcn_mfma_f32_16x16x32_bf16(vf2[u][0], pf[qt][0], o[qt][u], 0, 0, 0);
                o[qt][u] = __builtin_amdgcn_mfma_f32_16x16x32_bf16(vf2[u][1], pf[qt][1], o[qt][u], 0, 0, 0);
            }
    }

    // epilogue: O^T lane (q,n): query = i0+16qt+n, d = 16u+4q+r -> att2 A-frag
    for (int qt = 0; qt < 4; ++qt) {
        float inv = 1.0f / acc_l[qt][0];
        int pt = ti0 + qt;
        for (int u = 0; u < 4; ++u) {
            int kcA = 2 * h + (u >> 1);
            int q2 = 2 * (u & 1) + (q >> 1);
            uint2 pk;
            pk.x = pkbf(o[qt][u][0] * inv, o[qt][u][1] * inv);
            pk.y = pkbf(o[qt][u][2] * inv, o[qt][u][3] * inv);
            size_t addr = ((size_t)((b * 64 + pt) * 16 + kcA) * 512)
                          + (q2 * 16 + n) * 8 + 4 * (q & 1);
            *(uint2*)&att2[addr] = pk;
        }
    }
}

// ---------------- output projection + residual ----------------
__global__ __launch_bounds__(256, 4) void out_gemm(const unsigned short* __restrict__ att2,
                                                   const unsigned short* __restrict__ w0f,
                                                   const float* __restrict__ x,
                                                   float* __restrict__ out) {
    int b = blockIdx.x, ct = blockIdx.y, ptb = blockIdx.z;
    int tid = threadIdx.x, wave = tid >> 6, lane = tid & 63, q = lane >> 4, n = lane & 15;
    int pos0 = ptb * 64 + wave * 16;
    int c0 = ct * 64;
    int pt = ptb * 4 + wave;
    const unsigned short* abase = att2 + (size_t)(b * 64 + pt) * 16 * 512 + lane * 8;
    const unsigned short* wbase = w0f + (size_t)(c0 >> 4) * 16 * 512 + lane * 8;
    floatx4 acc[4];
    for (int s = 0; s < 4; ++s) acc[s] = (floatx4){0.f, 0.f, 0.f, 0.f};
    for (int g = 0; g < 4; ++g) {
        bf16x8 af[4], bfr[4][4];
        for (int k2 = 0; k2 < 4; ++k2) af[k2] = ldfrag(abase + (g * 4 + k2) * 512);
        for (int s = 0; s < 4; ++s)
            for (int k2 = 0; k2 < 4; ++k2)
                bfr[s][k2] = ldfrag(wbase + (s * 16 + g * 4 + k2) * 512);
        for (int k2 = 0; k2 < 4; ++k2)
            for (int s = 0; s < 4; ++s)
                acc[s] = __builtin_amdgcn_mfma_f32_16x16x32_bf16(af[k2], bfr[s][k2], acc[s], 0, 0, 0);
    }
    int p0q = pos0 + 4 * q;
    for (int s = 0; s < 4; ++s) {
        int c = c0 + 16 * s + n;
        size_t idx = ((size_t)b * CIN + c) * SEQ + p0q;
        floatx4 res = *(const floatx4*)&x[idx];
        floatx4 v = acc[s] + res;
        *(floatx4*)&out[idx] = v;
    }
}

// ---------------- launch ----------------
extern "C" void kernel_launch(void* const* d_in, const int* in_sizes, int n_in,
                              void* d_out, int out_size, void* d_ws, size_t ws_size,
                              hipStream_t stream) {
    const float* x  = (const float*)d_in[0];
    const float* Wq = (const float*)d_in[1];
    const float* Wk = (const float*)d_in[2];
    const float* Wv = (const float*)d_in[3];
    const float* R  = (const float*)d_in[4];
    const float* W0 = (const float*)d_in[5];
    float* out = (float*)d_out;

    char* ws = (char*)d_ws;
    size_t off = 0;
    unsigned short* Qt   = (unsigned short*)(ws + off); off += (size_t)NB * NH * SEQ * DKH * 2;
    unsigned short* Kf   = (unsigned short*)(ws + off); off += (size_t)NB * NH * SEQ * DKH * 2;
    unsigned short* Vf   = (unsigned short*)(ws + off); off += (size_t)NB * NH * SEQ * DKH * 2;
    unsigned short* att2 = (unsigned short*)(ws + off); off += (size_t)NB * SEQ * HDIM * 2;
    unsigned short* xt2  = (unsigned short*)(ws + off); off += (size_t)NB * SEQ * CIN * 2;
    unsigned short* w2   = (unsigned short*)(ws + off); off += (size_t)1536 * 128 * 2;
    unsigned short* w0f  = (unsigned short*)(ws + off); off += (size_t)128 * 512 * 2;
    float* biasF = (float*)(ws + off); off += (size_t)NH * 64 * 64 * 256 * 4;
    (void)ws_size; (void)in_sizes; (void)n_in; (void)out_size;

    prep_wb<<<9216, 256, 0, stream>>>(Wq, Wk, Wv, W0, R, w2, w0f, biasF);
    prep_xt<<<dim3(NB, 2, 16), 256, 0, stream>>>(x, xt2);
    qkv_gemm<<<dim3(NB, 24, 16), 256, 0, stream>>>(xt2, w2, Qt, Kf, Vf);
    attn_kernel<<<NB * NH * 4, 256, 0, stream>>>(Qt, Kf, Vf, biasF, att2);
    out_gemm<<<dim3(NB, 2, 16), 256, 0, stream>>>(att2, w0f, x, out);
}

// Round 10
// 214.532 us; speedup vs baseline: 1.5787x; 1.0691x over previous
//
#include <hip/hip_runtime.h>

// CvT block, MI355X bf16-MFMA implementation.
// B=32, C=128, L=32 (seq=1024), H=8, DK=64, HD=512, NLAYER=4.
// R10: (a) attn K/V double-buffered in LDS -> ONE barrier per key tile
// (was 2); (b) circulant bias compression: C-frag bias tile depends only on
// (dxx=(tq>>1 - tjk>>1)&31, tq&1, tjk&1) -> 128 tiles/head, 1MB total
// (L1/L2-resident), prep writes 33.5MB -> 1MB. Rest = R9 (transposed attn,
// register P, f32 bias as MFMA C operand, trunc-pack).

#define NB   32
#define NH   8
#define SEQ  1024
#define DKH  64
#define HDIM 512
#define CIN  128

// 0.125 * log2(e): folded into Wq and bias so scores are in exp2 domain.
#define SCL 0.18033688011112042f

typedef __bf16 bf16x8 __attribute__((ext_vector_type(8)));
typedef float floatx4 __attribute__((ext_vector_type(4)));
typedef unsigned short u16x8 __attribute__((ext_vector_type(8)));
typedef unsigned int uintx4 __attribute__((ext_vector_type(4)));

__device__ __forceinline__ unsigned short f2bf(float f) {
    union { float f; unsigned int u; } c; c.f = f;
    unsigned int u = c.u;
    return (unsigned short)((u + 0x7fffu + ((u >> 16) & 1u)) >> 16); // RNE
}
__device__ __forceinline__ bf16x8 ldfrag(const unsigned short* p) {
    u16x8 v = *reinterpret_cast<const u16x8*>(p);
    return __builtin_bit_cast(bf16x8, v);
}
// pack two f32 -> two RNE bf16; 'a' lands in the LOW short.
__device__ __forceinline__ unsigned int pkbf(float a, float b) {
    unsigned int ua = __builtin_bit_cast(unsigned int, a);
    unsigned int ub = __builtin_bit_cast(unsigned int, b);
    ua += 0x7fffu + ((ua >> 16) & 1u);
    ub += 0x7fffu + ((ub >> 16) & 1u);
    return __builtin_amdgcn_perm(ub, ua, 0x07060302u);
}
// truncation pack (P>0): one v_perm, no rounding adds.
__device__ __forceinline__ unsigned int pkbf_t(float a, float b) {
    return __builtin_amdgcn_perm(__builtin_bit_cast(unsigned int, b),
                                 __builtin_bit_cast(unsigned int, a), 0x07060302u);
}

// Fragment-order storage: 512-elem block = one wave fragment [lane][j].
// Kf (A-frag, m=key): frag (s,c): lane (q,n) j <-> K[key=16s+n][d=32c+8q+j]
// Vf (A-frag, m=d, permuted k): frag (u,c): lane (q,n) jj <->
//     V[key = 32c+16(jj>>2)+4q+(jj&3)][d=16u+n]   (matches P^T pack order)

// ---------------- prep: weights + compressed circulant bias ----------------
// blocks [0, 256): biasG f32 C-frag tiles, slot = ((h*32+dxx)*2+a)*2+bb:
//   biasG[slot*256 + lane*4 + r] = R[h][dxx][((a<<4)+n - (bb<<4)-4q-r)&31]*SCL
//   (the bias tile for any (tq,tjk) with (tq>>1-tjk>>1)&31==dxx, tq&1==a,
//    tjk&1==bb — query tiles never straddle a 32-boundary).
// blocks [256, 1280): weight casts; Wq scaled by SCL (exp2 domain).
__global__ __launch_bounds__(256) void prep_wb(const float* __restrict__ Wq,
                                               const float* __restrict__ Wk,
                                               const float* __restrict__ Wv,
                                               const float* __restrict__ W0,
                                               const float* __restrict__ R,
                                               unsigned short* __restrict__ w2,
                                               unsigned short* __restrict__ w0f,
                                               float* __restrict__ biasG) {
    if (blockIdx.x < 256) {
        int gidx = blockIdx.x * 256 + threadIdx.x;       // [0, 65536)
        int lane = gidx & 63, slot = gidx >> 6;          // slot in [0, 1024)
        int bb = slot & 1, a = (slot >> 1) & 1, dxx = (slot >> 2) & 31, h = slot >> 7;
        int q = lane >> 4, n = lane & 15;
        int iy = (a << 4) + n;
        const float* Rh = R + (h << 10) + (dxx << 5);
        floatx4 v;
        for (int r = 0; r < 4; ++r) {
            int jy = (bb << 4) + 4 * q + r;
            v[r] = Rh[(iy - jy) & 31] * SCL;
        }
        *(floatx4*)&biasG[(size_t)gidx * 4] = v;
    } else {
        int idx = (blockIdx.x - 256) * 256 + threadIdx.x;  // [0, 262144)
        if (idx < 196608) {
            int row = idx >> 7, col = idx & 127;
            float v;
            if (row < 512)       v = Wq[idx] * SCL;
            else if (row < 1024) v = Wk[idx - 65536];
            else                 v = Wv[idx - 131072];
            int rt = row >> 4, nr = row & 15, kc = col >> 5, qc = (col & 31) >> 3, jc = col & 7;
            w2[((rt * 4 + kc) * 512) + (qc * 16 + nr) * 8 + jc] = f2bf(v);
        } else {
            int idx2 = idx - 196608;
            int row = idx2 >> 9, col = idx2 & 511;
            int rt = row >> 4, nr = row & 15, kcA = col >> 5, qc = (col & 31) >> 3, jc = col & 7;
            w0f[((rt * 16 + kcA) * 512) + (qc * 16 + nr) * 8 + jc] = f2bf(W0[idx2]);
        }
    }
}

// xt2: x transposed+scaled, in B/A fragment order over (b, pt=pos/16, kc=c/32).
__global__ __launch_bounds__(256) void prep_xt(const float* __restrict__ x,
                                               unsigned short* __restrict__ xt2) {
    __shared__ float lds[64 * 65];
    int b = blockIdx.x, c0 = blockIdx.y * 64, p0 = blockIdx.z * 64;
    int t = threadIdx.x, tr = t >> 6, tc = t & 63;
    const float inv_layer = 0.44721359549995793f;  // 1/sqrt(5)
    for (int rr = 0; rr < 16; ++rr) {
        int cl = rr * 4 + tr;
        lds[cl * 65 + tc] = x[(b * CIN + c0 + cl) * SEQ + p0 + tc];
    }
    __syncthreads();
    for (int rr = 0; rr < 16; ++rr) {
        int pl = rr * 4 + tr;
        int pos = p0 + pl, c = c0 + tc;
        int pt = pos >> 4, np = pos & 15, kc = c >> 5, qc = (c & 31) >> 3, jc = c & 7;
        xt2[((size_t)((b * 64 + pt) * 4 + kc) * 512) + (qc * 16 + np) * 8 + jc] =
            f2bf(lds[tc * 65 + pl] * inv_layer);
    }
}

// ---------------- fused QKV projection ----------------
__global__ __launch_bounds__(256, 4) void qkv_gemm(const unsigned short* __restrict__ xt2,
                                                   const unsigned short* __restrict__ w2,
                                                   unsigned short* __restrict__ Qt,
                                                   unsigned short* __restrict__ Kf,
                                                   unsigned short* __restrict__ Vf) {
    int b = blockIdx.x, y = blockIdx.y, zt = blockIdx.z;
    int tid = threadIdx.x, wave = tid >> 6, lane = tid & 63, q = lane >> 4, n = lane & 15;
    floatx4 acc[4];
    for (int s = 0; s < 4; ++s) acc[s] = (floatx4){0.f, 0.f, 0.f, 0.f};
    bf16x8 af[4], bfr[4][4];
    if (y < 16) {
        int rt = y * 4 + wave;                       // wrow tile
        const unsigned short* wbase = w2 + (size_t)rt * 4 * 512 + lane * 8;
        const unsigned short* xbase = xt2 + (size_t)(b * 64 + zt * 4) * 4 * 512 + lane * 8;
        for (int kc = 0; kc < 4; ++kc) af[kc] = ldfrag(wbase + kc * 512);
        for (int s = 0; s < 4; ++s)
            for (int kc = 0; kc < 4; ++kc) bfr[s][kc] = ldfrag(xbase + (s * 4 + kc) * 512);
        for (int kc = 0; kc < 4; ++kc)
            for (int s = 0; s < 4; ++s)
                acc[s] = __builtin_amdgcn_mfma_f32_16x16x32_bf16(af[kc], bfr[s][kc], acc[s], 0, 0, 0);
        int wrow0 = y * 64 + wave * 16;
        int pos0 = zt * 64;
        if (y < 8) {
            int h = wrow0 >> 6;
            int d0 = (wrow0 & 63) + 4 * q;
            for (int s = 0; s < 4; ++s) {
                uint2 pk;
                pk.x = pkbf(acc[s][0], acc[s][1]);
                pk.y = pkbf(acc[s][2], acc[s][3]);
                int pos = pos0 + 16 * s + n;
                *(uint2*)&Qt[((size_t)(b * NH + h) * SEQ + pos) * DKH + d0] = pk;
            }
        } else {
            // K: d = wave*16+4q+r (regs), key = 16s+n. A-frag store.
            int h = (wrow0 >> 6) - 8;
            int bh = b * NH + h;
            int cd = wave >> 1;
            int qk = 2 * (wave & 1) + (q >> 1);
            int jk = 4 * (q & 1);
            for (int s = 0; s < 4; ++s) {
                uint2 pk;
                pk.x = pkbf(acc[s][0], acc[s][1]);
                pk.y = pkbf(acc[s][2], acc[s][3]);
                size_t addr = ((size_t)(bh * 16 + zt) * 8 + s * 2 + cd) * 512
                              + (qk * 16 + n) * 8 + jk;
                *(uint2*)&Kf[addr] = pk;
            }
        }
    } else {
        int pt = zt * 4 + wave;                      // pos tile
        const unsigned short* xbase = xt2 + (size_t)((b * 64 + pt) * 4) * 512 + lane * 8;
        int rtv0 = 64 + (y - 16) * 4;                // V wrow tiles start at row 1024
        const unsigned short* wbase = w2 + (size_t)rtv0 * 4 * 512 + lane * 8;
        for (int kc = 0; kc < 4; ++kc) af[kc] = ldfrag(xbase + kc * 512);
        for (int s = 0; s < 4; ++s)
            for (int kc = 0; kc < 4; ++kc) bfr[s][kc] = ldfrag(wbase + (s * 4 + kc) * 512);
        for (int kc = 0; kc < 4; ++kc)
            for (int s = 0; s < 4; ++s)
                acc[s] = __builtin_amdgcn_mfma_f32_16x16x32_bf16(af[kc], bfr[s][kc], acc[s], 0, 0, 0);
        // V: key = wave*16+4q+r (regs) -> Vf A-frag with PV k-permutation.
        int vrow0 = (y - 16) * 64;
        int cj = wave >> 1;
        int jj0 = 4 * (wave & 1);
        for (int s = 0; s < 4; ++s) {
            int vrow = vrow0 + 16 * s + n;
            int h = vrow >> 6, d = vrow & 63;
            int u = d >> 4, nl = d & 15;
            uint2 pk;
            pk.x = pkbf(acc[s][0], acc[s][1]);
            pk.y = pkbf(acc[s][2], acc[s][3]);
            size_t addr = ((size_t)((b * NH + h) * 16 + zt) * 8 + u * 2 + cj) * 512
                          + (q * 16 + nl) * 8 + jj0;
            *(uint2*)&Vf[addr] = pk;
        }
    }
}

// ---------------- attention (transposed, register P, double-buffered) ----------------
// WG = 256 queries (4 waves x 64, as 4 n-tiles of 16); key tiles of 64.
// gid&255 = (b,h) -> one head per XCD. S^T = K Q^T with compressed f32
// circulant bias as MFMA C operand; P^T trunc-packed in registers;
// O^T = V^T P^T; ONE barrier per key tile (LDS double buffer).
__global__ __launch_bounds__(256, 2) void attn_kernel(const unsigned short* __restrict__ Qt,
                                                      const unsigned short* __restrict__ Kf,
                                                      const unsigned short* __restrict__ Vf,
                                                      const float* __restrict__ biasG,
                                                      unsigned short* __restrict__ att2) {
    __shared__ alignas(16) unsigned short lds_k[2][8 * 512];   // A-frag K tiles
    __shared__ alignas(16) unsigned short lds_v[2][8 * 512];   // A-frag V tiles

    int gid = blockIdx.x;
    int bh = gid & 255, qb = gid >> 8;
    int b = bh >> 3, h = bh & 7;
    int tid = threadIdx.x, wave = tid >> 6, lane = tid & 63, q = lane >> 4, n = lane & 15;
    int i0 = qb * 256 + wave * 64;
    int ti0 = i0 >> 4;

    const unsigned short* qbase = Qt + (size_t)bh * SEQ * DKH;
    const unsigned short* kft = Kf + (size_t)bh * 16 * 4096;
    const unsigned short* vft = Vf + (size_t)bh * 16 * 4096;
    const float* bGh = biasG + ((size_t)h * 32 * 4 * 256) + lane * 4;  // per-head + lane

    // Q as B-fragments: lane (q,n): query = i0+16qt+n, d = c*32+8q+j
    bf16x8 aq[4][2];
    for (int qt = 0; qt < 4; ++qt)
        for (int c = 0; c < 2; ++c)
            aq[qt][c] = ldfrag(qbase + (i0 + 16 * qt + n) * DKH + c * 32 + q * 8);

    // all-ones A fragment for column-sum MFMA (l = 1^T P^T)
    u16x8 ones_u;
    for (int t = 0; t < 8; ++t) ones_u[t] = 0x3F80;
    bf16x8 vone = __builtin_bit_cast(bf16x8, ones_u);

    floatx4 o[4][4], acc_l[4];
    for (int qt = 0; qt < 4; ++qt) {
        acc_l[qt] = (floatx4){0.f, 0.f, 0.f, 0.f};
        for (int u = 0; u < 4; ++u) o[qt][u] = (floatx4){0.f, 0.f, 0.f, 0.f};
    }

    // stage tile 0 into buffer 0
    {
        const unsigned short* kp = kft + tid * 16;
        const unsigned short* vp = vft + tid * 16;
        u16x8 k0 = *(const u16x8*)kp, k1 = *(const u16x8*)(kp + 8);
        u16x8 v0 = *(const u16x8*)vp, v1 = *(const u16x8*)(vp + 8);
        *(u16x8*)&lds_k[0][tid * 16]     = k0;
        *(u16x8*)&lds_k[0][tid * 16 + 8] = k1;
        *(u16x8*)&lds_v[0][tid * 16]     = v0;
        *(u16x8*)&lds_v[0][tid * 16 + 8] = v1;
    }
    __syncthreads();

    for (int kt = 0; kt < 16; ++kt) {
        int cur = kt & 1;
        // prefetch next tile into registers (latency overlaps compute)
        u16x8 kpre0, kpre1, vpre0, vpre1;
        if (kt < 15) {
            const unsigned short* kp = kft + (kt + 1) * 4096 + tid * 16;
            const unsigned short* vp = vft + (kt + 1) * 4096 + tid * 16;
            kpre0 = *(const u16x8*)kp;  kpre1 = *(const u16x8*)(kp + 8);
            vpre0 = *(const u16x8*)vp;  vpre1 = *(const u16x8*)(vp + 8);
        }

        // compressed bias C-fragments: slot = dxx*1024 + a*512 + (s&1)*256 floats
        floatx4 bsv[4][4];
        for (int qt = 0; qt < 4; ++qt) {
            int tq = ti0 + qt;
            int a512 = (tq & 1) << 9;
            int e0 = (tq >> 1) - 2 * kt;
            for (int s = 0; s < 4; ++s) {
                int dxx = (e0 - (s >> 1)) & 31;
                bsv[qt][s] = *(const floatx4*)(bGh + (dxx << 10) + a512 + ((s & 1) << 8));
            }
        }

        // K fragments (shared across the 4 query tiles)
        bf16x8 kf2[4][2];
        for (int s = 0; s < 4; ++s)
            for (int c = 0; c < 2; ++c)
                kf2[s][c] = ldfrag(&lds_k[cur][(s * 2 + c) * 512 + lane * 8]);

        // S^T = K Q^T + bias^T (C-init); P^T = exp2 -> packed B-frags
        bf16x8 pf[4][2];
        for (int qt = 0; qt < 4; ++qt) {
            floatx4 sv[4];
            for (int s = 0; s < 4; ++s) {
                sv[s] = __builtin_amdgcn_mfma_f32_16x16x32_bf16(kf2[s][0], aq[qt][0], bsv[qt][s], 0, 0, 0);
                sv[s] = __builtin_amdgcn_mfma_f32_16x16x32_bf16(kf2[s][1], aq[qt][1], sv[s], 0, 0, 0);
            }
            for (int c = 0; c < 2; ++c) {
                uintx4 pu;
                pu[0] = pkbf_t(__builtin_amdgcn_exp2f(sv[2 * c][0]), __builtin_amdgcn_exp2f(sv[2 * c][1]));
                pu[1] = pkbf_t(__builtin_amdgcn_exp2f(sv[2 * c][2]), __builtin_amdgcn_exp2f(sv[2 * c][3]));
                pu[2] = pkbf_t(__builtin_amdgcn_exp2f(sv[2 * c + 1][0]), __builtin_amdgcn_exp2f(sv[2 * c + 1][1]));
                pu[3] = pkbf_t(__builtin_amdgcn_exp2f(sv[2 * c + 1][2]), __builtin_amdgcn_exp2f(sv[2 * c + 1][3]));
                pf[qt][c] = __builtin_bit_cast(bf16x8, pu);
            }
        }

        // V fragments, then O^T += V^T P^T ; l += 1^T P^T
        bf16x8 vf2[4][2];
        for (int u = 0; u < 4; ++u)
            for (int c = 0; c < 2; ++c)
                vf2[u][c] = ldfrag(&lds_v[cur][(u * 2 + c) * 512 + lane * 8]);
        for (int qt = 0; qt < 4; ++qt) {
            acc_l[qt] = __builtin_amdgcn_mfma_f32_16x16x32_bf16(vone, pf[qt][0], acc_l[qt], 0, 0, 0);
            acc_l[qt] = __builtin_amdgcn_mfma_f32_16x16x32_bf16(vone, pf[qt][1], acc_l[qt], 0, 0, 0);
        }
        for (int u = 0; u < 4; ++u)
            for (int qt = 0; qt < 4; ++qt) {
                o[qt][u] = __builtin_amdgcn_mfma_f32_16x16x32_bf16(vf2[u][0], pf[qt][0], o[qt][u], 0, 0, 0);
                o[qt][u] = __builtin_amdgcn_mfma_f32_16x16x32_bf16(vf2[u][1], pf[qt][1], o[qt][u], 0, 0, 0);
            }

        // store prefetched tile into the other buffer, then ONE barrier
        if (kt < 15) {
            int nxt = cur ^ 1;
            *(u16x8*)&lds_k[nxt][tid * 16]     = kpre0;
            *(u16x8*)&lds_k[nxt][tid * 16 + 8] = kpre1;
            *(u16x8*)&lds_v[nxt][tid * 16]     = vpre0;
            *(u16x8*)&lds_v[nxt][tid * 16 + 8] = vpre1;
        }
        __syncthreads();
    }

    // epilogue: O^T lane (q,n): query = i0+16qt+n, d = 16u+4q+r -> att2 A-frag
    for (int qt = 0; qt < 4; ++qt) {
        float inv = 1.0f / acc_l[qt][0];
        int pt = ti0 + qt;
        for (int u = 0; u < 4; ++u) {
            int kcA = 2 * h + (u >> 1);
            int q2 = 2 * (u & 1) + (q >> 1);
            uint2 pk;
            pk.x = pkbf(o[qt][u][0] * inv, o[qt][u][1] * inv);
            pk.y = pkbf(o[qt][u][2] * inv, o[qt][u][3] * inv);
            size_t addr = ((size_t)((b * 64 + pt) * 16 + kcA) * 512)
                          + (q2 * 16 + n) * 8 + 4 * (q & 1);
            *(uint2*)&att2[addr] = pk;
        }
    }
}

// ---------------- output projection + residual ----------------
__global__ __launch_bounds__(256, 4) void out_gemm(const unsigned short* __restrict__ att2,
                                                   const unsigned short* __restrict__ w0f,
                                                   const float* __restrict__ x,
                                                   float* __restrict__ out) {
    int b = blockIdx.x, ct = blockIdx.y, ptb = blockIdx.z;
    int tid = threadIdx.x, wave = tid >> 6, lane = tid & 63, q = lane >> 4, n = lane & 15;
    int pos0 = ptb * 64 + wave * 16;
    int c0 = ct * 64;
    int pt = ptb * 4 + wave;
    const unsigned short* abase = att2 + (size_t)(b * 64 + pt) * 16 * 512 + lane * 8;
    const unsigned short* wbase = w0f + (size_t)(c0 >> 4) * 16 * 512 + lane * 8;
    floatx4 acc[4];
    for (int s = 0; s < 4; ++s) acc[s] = (floatx4){0.f, 0.f, 0.f, 0.f};
    for (int g = 0; g < 4; ++g) {
        bf16x8 af[4], bfr[4][4];
        for (int k2 = 0; k2 < 4; ++k2) af[k2] = ldfrag(abase + (g * 4 + k2) * 512);
        for (int s = 0; s < 4; ++s)
            for (int k2 = 0; k2 < 4; ++k2)
                bfr[s][k2] = ldfrag(wbase + (s * 16 + g * 4 + k2) * 512);
        for (int k2 = 0; k2 < 4; ++k2)
            for (int s = 0; s < 4; ++s)
                acc[s] = __builtin_amdgcn_mfma_f32_16x16x32_bf16(af[k2], bfr[s][k2], acc[s], 0, 0, 0);
    }
    int p0q = pos0 + 4 * q;
    for (int s = 0; s < 4; ++s) {
        int c = c0 + 16 * s + n;
        size_t idx = ((size_t)b * CIN + c) * SEQ + p0q;
        floatx4 res = *(const floatx4*)&x[idx];
        floatx4 v = acc[s] + res;
        *(floatx4*)&out[idx] = v;
    }
}

// ---------------- launch ----------------
extern "C" void kernel_launch(void* const* d_in, const int* in_sizes, int n_in,
                              void* d_out, int out_size, void* d_ws, size_t ws_size,
                              hipStream_t stream) {
    const float* x  = (const float*)d_in[0];
    const float* Wq = (const float*)d_in[1];
    const float* Wk = (const float*)d_in[2];
    const float* Wv = (const float*)d_in[3];
    const float* R  = (const float*)d_in[4];
    const float* W0 = (const float*)d_in[5];
    float* out = (float*)d_out;

    char* ws = (char*)d_ws;
    size_t off = 0;
    unsigned short* Qt   = (unsigned short*)(ws + off); off += (size_t)NB * NH * SEQ * DKH * 2;
    unsigned short* Kf   = (unsigned short*)(ws + off); off += (size_t)NB * NH * SEQ * DKH * 2;
    unsigned short* Vf   = (unsigned short*)(ws + off); off += (size_t)NB * NH * SEQ * DKH * 2;
    unsigned short* att2 = (unsigned short*)(ws + off); off += (size_t)NB * SEQ * HDIM * 2;
    unsigned short* xt2  = (unsigned short*)(ws + off); off += (size_t)NB * SEQ * CIN * 2;
    unsigned short* w2   = (unsigned short*)(ws + off); off += (size_t)1536 * 128 * 2;
    unsigned short* w0f  = (unsigned short*)(ws + off); off += (size_t)128 * 512 * 2;
    float* biasG = (float*)(ws + off); off += (size_t)NH * 32 * 4 * 256 * 4;   // 1 MB
    (void)ws_size; (void)in_sizes; (void)n_in; (void)out_size;

    prep_wb<<<1280, 256, 0, stream>>>(Wq, Wk, Wv, W0, R, w2, w0f, biasG);
    prep_xt<<<dim3(NB, 2, 16), 256, 0, stream>>>(x, xt2);
    qkv_gemm<<<dim3(NB, 24, 16), 256, 0, stream>>>(xt2, w2, Qt, Kf, Vf);
    attn_kernel<<<NB * NH * 4, 256, 0, stream>>>(Qt, Kf, Vf, biasG, att2);
    out_gemm<<<dim3(NB, 2, 16), 256, 0, stream>>>(att2, w0f, x, out);
}